// Round 1
// baseline (31878.271 us; speedup 1.0000x reference)
//
#include <hip/hip_runtime.h>
#include <hip/hip_cooperative_groups.h>

typedef __attribute__((ext_vector_type(4))) float f32x4;
typedef __attribute__((ext_vector_type(8))) short short8;
typedef __attribute__((ext_vector_type(8))) unsigned short ushort8;
typedef __attribute__((ext_vector_type(4))) unsigned short ushort4v;
typedef __attribute__((ext_vector_type(4))) unsigned int uint4v;
typedef unsigned short ushort;

__device__ __forceinline__ ushort f2bf(float f) {
  union { float f; unsigned u; } v; v.f = f;
  unsigned u = v.u;
  return (ushort)((u + 0x7FFFu + ((u >> 16) & 1u)) >> 16);  // RNE
}
__device__ __forceinline__ float bf2f(ushort s) {
  union { unsigned u; float f; } v; v.u = ((unsigned)s) << 16;
  return v.f;
}

// ---------------- prep kernels ----------------

// dst[c][r] = bf16(src[r][c]); src [R][C] f32, dst [C][R] bf16
__global__ void transpose_cvt(const float* __restrict__ src, ushort* __restrict__ dst,
                              int R, int C) {
  __shared__ float tile[32][33];
  int bx = blockIdx.x * 32;  // col in src
  int by = blockIdx.y * 32;  // row in src
  int tx = threadIdx.x, ty = threadIdx.y;
#pragma unroll
  for (int i = 0; i < 32; i += 8)
    tile[ty + i][tx] = src[(size_t)(by + ty + i) * C + bx + tx];
  __syncthreads();
#pragma unroll
  for (int i = 0; i < 32; i += 8)
    dst[(size_t)(bx + ty + i) * R + by + tx] = f2bf(tile[tx][ty + i]);
}

__global__ void concat_bias(const float* a, const float* b, const float* c, const float* d,
                            float* __restrict__ o) {
  int i = blockIdx.x * 256 + threadIdx.x;  // 4096 total
  int g = i >> 10, n = i & 1023;
  float v = (g == 0) ? a[n] : (g == 1) ? b[n] : (g == 2) ? c[n] : d[n];
  o[i] = v;
}

__global__ void init_h(const float* __restrict__ h0, ushort* __restrict__ hA) {
  int i = blockIdx.x * 256 + threadIdx.x;  // 16384 threads * 4 elems
  f32x4 v = *(const f32x4*)(h0 + (size_t)i * 4);
  ushort4v w;
  w.x = f2bf(v.x); w.y = f2bf(v.y); w.z = f2bf(v.z); w.w = f2bf(v.w);
  *(ushort4v*)(hA + (size_t)i * 4) = w;
}

// ---------------- phase 1: xp = x @ Wx + b  (bf16 MFMA) ----------------
// X [32768][512] f32 (row = b*512+t), Bt = WxT [4096][512] bf16, Out [t*64+b][4096] bf16
__global__ __launch_bounds__(256) void gemm_xp(
    const float* __restrict__ X,
    const ushort* __restrict__ Bt,
    const float* __restrict__ bias,
    ushort* __restrict__ Out) {
  __shared__ ushort As[128][40];  // +8 pad kills bank conflicts
  __shared__ ushort Bs[128][40];
  const int tid = threadIdx.x;
  const int lane = tid & 63;
  const int wave = tid >> 6;
  const int wr = wave >> 1, wc = wave & 1;  // 2x2 wave grid, 64x64 each
  const int row0 = blockIdx.y * 128, col0 = blockIdx.x * 128;
  const int l15 = lane & 15, kg = (lane >> 4) * 8;
  f32x4 acc[4][4] = {};
  for (int k0 = 0; k0 < 512; k0 += 32) {
#pragma unroll
    for (int r = 0; r < 2; ++r) {
      int cid = tid + (r << 8);
      int row = cid >> 2, kch = (cid & 3) << 3;
      const float* ap = X + (size_t)(row0 + row) * 512 + k0 + kch;
      f32x4 v0 = *(const f32x4*)ap;
      f32x4 v1 = *(const f32x4*)(ap + 4);
      ushort8 w;
      w[0] = f2bf(v0.x); w[1] = f2bf(v0.y); w[2] = f2bf(v0.z); w[3] = f2bf(v0.w);
      w[4] = f2bf(v1.x); w[5] = f2bf(v1.y); w[6] = f2bf(v1.z); w[7] = f2bf(v1.w);
      *(ushort8*)&As[row][kch] = w;
      uint4v vb = *(const uint4v*)(Bt + (size_t)(col0 + row) * 512 + k0 + kch);
      *(uint4v*)&Bs[row][kch] = vb;
    }
    __syncthreads();
    short8 af[4], bfv[4];
#pragma unroll
    for (int fm = 0; fm < 4; ++fm)
      af[fm] = *(const short8*)&As[wr * 64 + fm * 16 + l15][kg];
#pragma unroll
    for (int fn = 0; fn < 4; ++fn)
      bfv[fn] = *(const short8*)&Bs[wc * 64 + fn * 16 + l15][kg];
#pragma unroll
    for (int fm = 0; fm < 4; ++fm)
#pragma unroll
      for (int fn = 0; fn < 4; ++fn)
        acc[fm][fn] = __builtin_amdgcn_mfma_f32_16x16x32_bf16(af[fm], bfv[fn], acc[fm][fn], 0, 0, 0);
    __syncthreads();
  }
#pragma unroll
  for (int fm = 0; fm < 4; ++fm) {
#pragma unroll
    for (int fn = 0; fn < 4; ++fn) {
#pragma unroll
      for (int r = 0; r < 4; ++r) {
        int gr = row0 + wr * 64 + fm * 16 + ((lane >> 4) << 2) + r;  // D row
        int gc = col0 + wc * 64 + fn * 16 + l15;                     // D col
        int b = gr >> 9, t = gr & 511;                               // gr = b*512 + t
        Out[(size_t)(t * 64 + b) * 4096 + gc] = f2bf(acc[fm][fn][r] + bias[gc]);
      }
    }
  }
}

// ---------------- phase 2: persistent cooperative recurrence ----------------
// grid = 256 blocks: bg = blk>>7 (batch half, 32), s = blk&127 (8 units: n = s*8+u)
// block cols c in [0,32): c = g*8 + u  (g = gate f/i/o/c)
__global__ __launch_bounds__(256) void lstm_rec(
    const ushort* __restrict__ xp,   // [512*64][4096] bf16, row = t*64+b
    const ushort* __restrict__ whT,  // [4096][1024] bf16 (gate-major cols)
    const float* __restrict__ c0,
    const float* __restrict__ wcf,
    const float* __restrict__ wci,
    const float* __restrict__ wco,
    ushort* __restrict__ hA,         // [64][1024] bf16 ping
    ushort* __restrict__ hB,         // pong
    float* __restrict__ out) {       // [64][512][1024] f32
  __shared__ ushort wh_s[32][1032];  // [col][k], +8 pad
  __shared__ ushort h_s[32][1032];   // [batch][k], +8 pad
  __shared__ float G[32][32];        // gate exchange [batch][col]

  const int tid = threadIdx.x;
  const int blk = blockIdx.x;
  const int bg = blk >> 7;
  const int s = blk & 127;
  const int lane = tid & 63;
  const int wave = tid >> 6;
  const int mi = wave >> 1, ni = wave & 1;  // wave tile: batches mi*16.., cols ni*16..

  // load Wh slice once: block col c -> global col (c>>3)*1024 + s*8 + (c&7)
#pragma unroll
  for (int r = 0; r < 16; ++r) {
    int cid = tid + (r << 8);
    int c = cid >> 7, kc = cid & 127;
    int gcol = ((c >> 3) << 10) + s * 8 + (c & 7);
    uint4v v = *(const uint4v*)(whT + (size_t)gcol * 1024 + kc * 8);
    *(uint4v*)&wh_s[c][kc * 8] = v;
  }

  const int b_l = tid >> 3;  // 0..31
  const int u = tid & 7;     // 0..7
  const int bG = bg * 32 + b_l;
  const int n = s * 8 + u;
  float c_val = c0[(size_t)bG * 1024 + n];
  const float pf = wcf[n], pi = wci[n], po = wco[n];

  const int arow = mi * 16 + (lane & 15);
  const int bcol = ni * 16 + (lane & 15);
  const int kg = (lane >> 4) * 8;

  cooperative_groups::grid_group grid = cooperative_groups::this_grid();
  __syncthreads();

  for (int t = 0; t < 512; ++t) {
    const ushort* hprev = (t & 1) ? hB : hA;
    ushort* hnext = (t & 1) ? hA : hB;

    // stage h[bg*32 .. +32][1024] into LDS
#pragma unroll
    for (int r = 0; r < 16; ++r) {
      int cid = tid + (r << 8);
      int row = cid >> 7, kc = cid & 127;
      uint4v v = *(const uint4v*)(hprev + (size_t)(bg * 32 + row) * 1024 + kc * 8);
      *(uint4v*)&h_s[row][kc * 8] = v;
    }
    __syncthreads();

    f32x4 acc0 = {0.f, 0.f, 0.f, 0.f}, acc1 = {0.f, 0.f, 0.f, 0.f};
#pragma unroll
    for (int kk = 0; kk < 32; kk += 2) {
      short8 a0 = *(const short8*)&h_s[arow][kk * 32 + kg];
      short8 b0 = *(const short8*)&wh_s[bcol][kk * 32 + kg];
      acc0 = __builtin_amdgcn_mfma_f32_16x16x32_bf16(a0, b0, acc0, 0, 0, 0);
      short8 a1 = *(const short8*)&h_s[arow][kk * 32 + 32 + kg];
      short8 b1 = *(const short8*)&wh_s[bcol][kk * 32 + 32 + kg];
      acc1 = __builtin_amdgcn_mfma_f32_16x16x32_bf16(a1, b1, acc1, 0, 0, 0);
    }
    f32x4 acc = acc0 + acc1;
#pragma unroll
    for (int r = 0; r < 4; ++r) {
      int b = mi * 16 + ((lane >> 4) << 2) + r;
      G[b][ni * 16 + (lane & 15)] = acc[r];
    }
    __syncthreads();

    // elementwise gate update: one (batch, unit) per thread
    size_t xbase = (size_t)(t * 64 + bG) * 4096 + n;
    float gf = G[b_l][u] + bf2f(xp[xbase]);
    float gi = G[b_l][8 + u] + bf2f(xp[xbase + 1024]);
    float go = G[b_l][16 + u] + bf2f(xp[xbase + 2048]);
    float gc = G[b_l][24 + u] + bf2f(xp[xbase + 3072]);
    float f = 1.f / (1.f + __expf(-(gf + pf * c_val)));
    float i = 1.f / (1.f + __expf(-(gi + pi * c_val)));
    float ct = 2.f / (1.f + __expf(-2.f * gc)) - 1.f;
    float cn = f * c_val + i * ct;
    float o = 1.f / (1.f + __expf(-(go + po * cn)));
    float h = o * (2.f / (1.f + __expf(-2.f * cn)) - 1.f);
    c_val = cn;
    hnext[(size_t)bG * 1024 + n] = f2bf(h);
    out[(size_t)(bG * 512 + t) * 1024 + n] = h;

    __threadfence();
    grid.sync();
  }
}

// ---------------- launcher ----------------
extern "C" void kernel_launch(void* const* d_in, const int* in_sizes, int n_in,
                              void* d_out, int out_size, void* d_ws, size_t ws_size,
                              hipStream_t stream) {
  const float* x = (const float*)d_in[0];
  const float* c0 = (const float*)d_in[1];
  const float* h0 = (const float*)d_in[2];
  const float* Wfx = (const float*)d_in[3];
  const float* bfp = (const float*)d_in[4];
  const float* Wix = (const float*)d_in[5];
  const float* bip = (const float*)d_in[6];
  const float* Wox = (const float*)d_in[7];
  const float* bop = (const float*)d_in[8];
  const float* Wcx = (const float*)d_in[9];
  const float* bcp = (const float*)d_in[10];
  const float* Wfh = (const float*)d_in[11];
  const float* Wih = (const float*)d_in[12];
  const float* Woh = (const float*)d_in[13];
  const float* Wch = (const float*)d_in[14];
  const float* wcf = (const float*)d_in[15];
  const float* wci = (const float*)d_in[16];
  const float* wco = (const float*)d_in[17];
  float* out = (float*)d_out;

  char* ws = (char*)d_ws;
  ushort* xp = (ushort*)(ws + 0);                  // 268,435,456 B
  ushort* WxT = (ushort*)(ws + 268435456ULL);      // 4,194,304 B
  ushort* WhT = (ushort*)(ws + 272629760ULL);      // 8,388,608 B
  float* bias = (float*)(ws + 281018368ULL);       // 16,384 B
  ushort* hA = (ushort*)(ws + 281034752ULL);       // 131,072 B
  ushort* hB = (ushort*)(ws + 281165824ULL);       // 131,072 B
  if (ws_size < 281296896ULL) return;              // need ~268.3 MiB

  const float* wxs[4] = {Wfx, Wix, Wox, Wcx};
  for (int g = 0; g < 4; ++g)
    transpose_cvt<<<dim3(32, 16), dim3(32, 8), 0, stream>>>(
        wxs[g], WxT + (size_t)g * 1024 * 512, 512, 1024);
  const float* whs[4] = {Wfh, Wih, Woh, Wch};
  for (int g = 0; g < 4; ++g)
    transpose_cvt<<<dim3(32, 32), dim3(32, 8), 0, stream>>>(
        whs[g], WhT + (size_t)g * 1024 * 1024, 1024, 1024);
  concat_bias<<<16, 256, 0, stream>>>(bfp, bip, bop, bcp, bias);
  init_h<<<64, 256, 0, stream>>>(h0, hA);
  gemm_xp<<<dim3(32, 256), 256, 0, stream>>>(x, WxT, bias, xp);

  void* args[9];
  args[0] = (void*)&xp;
  args[1] = (void*)&WhT;
  args[2] = (void*)&c0;
  args[3] = (void*)&wcf;
  args[4] = (void*)&wci;
  args[5] = (void*)&wco;
  args[6] = (void*)&hA;
  args[7] = (void*)&hB;
  args[8] = (void*)&out;
  hipLaunchCooperativeKernel((void*)lstm_rec, dim3(256), dim3(256), args, 0, stream);
}

// Round 2
// 8800.549 us; speedup vs baseline: 3.6223x; 3.6223x over previous
//
#include <hip/hip_runtime.h>

typedef __attribute__((ext_vector_type(4))) float f32x4;
typedef __attribute__((ext_vector_type(8))) short short8;
typedef __attribute__((ext_vector_type(8))) unsigned short ushort8;
typedef __attribute__((ext_vector_type(4))) unsigned short ushort4v;
typedef __attribute__((ext_vector_type(4))) unsigned int uint4v;
typedef unsigned short ushort;

__device__ __forceinline__ ushort f2bf(float f) {
  union { float f; unsigned u; } v; v.f = f;
  unsigned u = v.u;
  return (ushort)((u + 0x7FFFu + ((u >> 16) & 1u)) >> 16);  // RNE
}
__device__ __forceinline__ float bf2f(ushort s) {
  union { unsigned u; float f; } v; v.u = ((unsigned)s) << 16;
  return v.f;
}

// ---------------- prep kernels ----------------

// dst[c][r] = bf16(src[r][c]); src [R][C] f32, dst [C][R] bf16
__global__ void transpose_cvt(const float* __restrict__ src, ushort* __restrict__ dst,
                              int R, int C) {
  __shared__ float tile[32][33];
  int bx = blockIdx.x * 32;  // col in src
  int by = blockIdx.y * 32;  // row in src
  int tx = threadIdx.x, ty = threadIdx.y;
#pragma unroll
  for (int i = 0; i < 32; i += 8)
    tile[ty + i][tx] = src[(size_t)(by + ty + i) * C + bx + tx];
  __syncthreads();
#pragma unroll
  for (int i = 0; i < 32; i += 8)
    dst[(size_t)(bx + ty + i) * R + by + tx] = f2bf(tile[tx][ty + i]);
}

__global__ void concat_bias(const float* a, const float* b, const float* c, const float* d,
                            float* __restrict__ o) {
  int i = blockIdx.x * 256 + threadIdx.x;  // 4096 total
  int g = i >> 10, n = i & 1023;
  float v = (g == 0) ? a[n] : (g == 1) ? b[n] : (g == 2) ? c[n] : d[n];
  o[i] = v;
}

__global__ void init_h(const float* __restrict__ h0, ushort* __restrict__ hA) {
  int i = blockIdx.x * 256 + threadIdx.x;  // 16384 threads * 4 elems
  f32x4 v = *(const f32x4*)(h0 + (size_t)i * 4);
  ushort4v w;
  w.x = f2bf(v.x); w.y = f2bf(v.y); w.z = f2bf(v.z); w.w = f2bf(v.w);
  *(ushort4v*)(hA + (size_t)i * 4) = w;
}

// ---------------- phase 1: xp = x @ Wx + b  (bf16 MFMA) ----------------
// X [32768][512] f32 (row = b*512+t), Bt = WxT [4096][512] bf16, Out [t*64+b][4096] bf16
__global__ __launch_bounds__(256) void gemm_xp(
    const float* __restrict__ X,
    const ushort* __restrict__ Bt,
    const float* __restrict__ bias,
    ushort* __restrict__ Out) {
  __shared__ ushort As[128][40];  // +8 pad kills bank conflicts
  __shared__ ushort Bs[128][40];
  const int tid = threadIdx.x;
  const int lane = tid & 63;
  const int wave = tid >> 6;
  const int wr = wave >> 1, wc = wave & 1;  // 2x2 wave grid, 64x64 each
  const int row0 = blockIdx.y * 128, col0 = blockIdx.x * 128;
  const int l15 = lane & 15, kg = (lane >> 4) * 8;
  f32x4 acc[4][4] = {};
  for (int k0 = 0; k0 < 512; k0 += 32) {
#pragma unroll
    for (int r = 0; r < 2; ++r) {
      int cid = tid + (r << 8);
      int row = cid >> 2, kch = (cid & 3) << 3;
      const float* ap = X + (size_t)(row0 + row) * 512 + k0 + kch;
      f32x4 v0 = *(const f32x4*)ap;
      f32x4 v1 = *(const f32x4*)(ap + 4);
      ushort8 w;
      w[0] = f2bf(v0.x); w[1] = f2bf(v0.y); w[2] = f2bf(v0.z); w[3] = f2bf(v0.w);
      w[4] = f2bf(v1.x); w[5] = f2bf(v1.y); w[6] = f2bf(v1.z); w[7] = f2bf(v1.w);
      *(ushort8*)&As[row][kch] = w;
      uint4v vb = *(const uint4v*)(Bt + (size_t)(col0 + row) * 512 + k0 + kch);
      *(uint4v*)&Bs[row][kch] = vb;
    }
    __syncthreads();
    short8 af[4], bfv[4];
#pragma unroll
    for (int fm = 0; fm < 4; ++fm)
      af[fm] = *(const short8*)&As[wr * 64 + fm * 16 + l15][kg];
#pragma unroll
    for (int fn = 0; fn < 4; ++fn)
      bfv[fn] = *(const short8*)&Bs[wc * 64 + fn * 16 + l15][kg];
#pragma unroll
    for (int fm = 0; fm < 4; ++fm)
#pragma unroll
      for (int fn = 0; fn < 4; ++fn)
        acc[fm][fn] = __builtin_amdgcn_mfma_f32_16x16x32_bf16(af[fm], bfv[fn], acc[fm][fn], 0, 0, 0);
    __syncthreads();
  }
#pragma unroll
  for (int fm = 0; fm < 4; ++fm) {
#pragma unroll
    for (int fn = 0; fn < 4; ++fn) {
#pragma unroll
      for (int r = 0; r < 4; ++r) {
        int gr = row0 + wr * 64 + fm * 16 + ((lane >> 4) << 2) + r;  // D row
        int gc = col0 + wc * 64 + fn * 16 + l15;                     // D col
        int b = gr >> 9, t = gr & 511;                               // gr = b*512 + t
        Out[(size_t)(t * 64 + b) * 4096 + gc] = f2bf(acc[fm][fn][r] + bias[gc]);
      }
    }
  }
}

// ---------------- custom per-group grid barrier ----------------
// Mirrors __ockl_grid_sync fencing (wbl2+inv via __threadfence) but polls with
// s_sleep(1) (64-cyc) instead of ockl's exponential backoff (the 58us/step cost).
__device__ __forceinline__ void grid_bar(unsigned* cnt, unsigned* gen,
                                         unsigned nblk, unsigned my) {
  __syncthreads();  // all threads' h/out stores drained (waitcnt before s_barrier)
  if (threadIdx.x == 0) {
    __threadfence();  // release: write back this XCD's L2 (h, out visible device-wide)
    unsigned prev = __hip_atomic_fetch_add(cnt, 1u, __ATOMIC_RELAXED,
                                           __HIP_MEMORY_SCOPE_AGENT);
    if (prev == nblk - 1u) {
      __hip_atomic_store(cnt, 0u, __ATOMIC_RELAXED, __HIP_MEMORY_SCOPE_AGENT);
      __hip_atomic_store(gen, my + 1u, __ATOMIC_RELEASE, __HIP_MEMORY_SCOPE_AGENT);
      __threadfence();  // acquire side for ourselves: invalidate stale h lines
    } else {
      while (__hip_atomic_load(gen, __ATOMIC_RELAXED, __HIP_MEMORY_SCOPE_AGENT) < my + 1u)
        __builtin_amdgcn_s_sleep(1);
      __threadfence();  // acquire: invalidate L2 so h reads are fresh
    }
  }
  __syncthreads();
}

// ---------------- phase 2: persistent recurrence ----------------
// grid = 256 blocks: bg = blk>>7 (batch half, 32), s = blk&127 (8 units: n = s*8+u)
// block cols c in [0,32): c = g*8 + u  (g = gate f/i/o/c)
__global__ __launch_bounds__(256) void lstm_rec(
    const ushort* __restrict__ xp,   // [512*64][4096] bf16, row = t*64+b
    const ushort* __restrict__ whT,  // [4096][1024] bf16 (gate-major cols)
    const float* __restrict__ c0,
    const float* __restrict__ wcf,
    const float* __restrict__ wci,
    const float* __restrict__ wco,
    ushort* __restrict__ hA,         // [64][1024] bf16 ping
    ushort* __restrict__ hB,         // pong
    float* __restrict__ out,         // [64][512][1024] f32
    unsigned* __restrict__ bar) {    // 2 x {cnt, gen} in separate cachelines
  __shared__ ushort wh_s[32][1032];  // [col][k], +8 pad
  __shared__ ushort h_s[32][1032];   // [batch][k], +8 pad
  __shared__ float G[32][32];        // gate exchange [batch][col]

  const int tid = threadIdx.x;
  const int blk = blockIdx.x;
  const int bg = blk >> 7;
  const int s = blk & 127;
  const int lane = tid & 63;
  const int wave = tid >> 6;
  const int mi = wave >> 1, ni = wave & 1;  // wave tile: batches mi*16.., cols ni*16..

  unsigned* bcnt = bar + bg * 64;       // 256B apart per group
  unsigned* bgen = bar + bg * 64 + 32;  // cnt/gen in different cachelines

  // load Wh slice once: block col c -> global col (c>>3)*1024 + s*8 + (c&7)
#pragma unroll
  for (int r = 0; r < 16; ++r) {
    int cid = tid + (r << 8);
    int c = cid >> 7, kc = cid & 127;
    int gcol = ((c >> 3) << 10) + s * 8 + (c & 7);
    uint4v v = *(const uint4v*)(whT + (size_t)gcol * 1024 + kc * 8);
    *(uint4v*)&wh_s[c][kc * 8] = v;
  }

  const int b_l = tid >> 3;  // 0..31
  const int u = tid & 7;     // 0..7
  const int bG = bg * 32 + b_l;
  const int n = s * 8 + u;
  float c_val = c0[(size_t)bG * 1024 + n];
  const float pf = wcf[n], pi = wci[n], po = wco[n];

  const int arow = mi * 16 + (lane & 15);
  const int bcol = ni * 16 + (lane & 15);
  const int kg = (lane >> 4) * 8;

  // prefetch xp for t=0
  const size_t xbase0 = (size_t)bG * 4096 + n;
  ushort px0 = xp[xbase0], px1 = xp[xbase0 + 1024];
  ushort px2 = xp[xbase0 + 2048], px3 = xp[xbase0 + 3072];

  __syncthreads();

  for (int t = 0; t < 512; ++t) {
    const ushort* hprev = (t & 1) ? hB : hA;
    ushort* hnext = (t & 1) ? hA : hB;

    // stage h[bg*32 .. +32][1024] into LDS
#pragma unroll
    for (int r = 0; r < 16; ++r) {
      int cid = tid + (r << 8);
      int row = cid >> 7, kc = cid & 127;
      uint4v v = *(const uint4v*)(hprev + (size_t)(bg * 32 + row) * 1024 + kc * 8);
      *(uint4v*)&h_s[row][kc * 8] = v;
    }
    __syncthreads();

    f32x4 acc0 = {0.f, 0.f, 0.f, 0.f}, acc1 = {0.f, 0.f, 0.f, 0.f};
#pragma unroll
    for (int kk = 0; kk < 32; kk += 2) {
      short8 a0 = *(const short8*)&h_s[arow][kk * 32 + kg];
      short8 b0 = *(const short8*)&wh_s[bcol][kk * 32 + kg];
      acc0 = __builtin_amdgcn_mfma_f32_16x16x32_bf16(a0, b0, acc0, 0, 0, 0);
      short8 a1 = *(const short8*)&h_s[arow][kk * 32 + 32 + kg];
      short8 b1 = *(const short8*)&wh_s[bcol][kk * 32 + 32 + kg];
      acc1 = __builtin_amdgcn_mfma_f32_16x16x32_bf16(a1, b1, acc1, 0, 0, 0);
    }
    f32x4 acc = acc0 + acc1;
#pragma unroll
    for (int r = 0; r < 4; ++r) {
      int b = mi * 16 + ((lane >> 4) << 2) + r;
      G[b][ni * 16 + (lane & 15)] = acc[r];
    }
    __syncthreads();

    // elementwise gate update: one (batch, unit) per thread
    float gf = G[b_l][u] + bf2f(px0);
    float gi = G[b_l][8 + u] + bf2f(px1);
    float go = G[b_l][16 + u] + bf2f(px2);
    float gc = G[b_l][24 + u] + bf2f(px3);
    float f = 1.f / (1.f + __expf(-(gf + pf * c_val)));
    float i = 1.f / (1.f + __expf(-(gi + pi * c_val)));
    float ct = 2.f / (1.f + __expf(-2.f * gc)) - 1.f;
    float cn = f * c_val + i * ct;
    float o = 1.f / (1.f + __expf(-(go + po * cn)));
    float h = o * (2.f / (1.f + __expf(-2.f * cn)) - 1.f);
    c_val = cn;
    hnext[(size_t)bG * 1024 + n] = f2bf(h);
    out[(size_t)(bG * 512 + t) * 1024 + n] = h;

    if (t < 511) {
      // prefetch next step's xp; HBM latency hides under the barrier wait
      size_t xb = xbase0 + (size_t)(t + 1) * 262144;  // 64*4096
      px0 = xp[xb]; px1 = xp[xb + 1024]; px2 = xp[xb + 2048]; px3 = xp[xb + 3072];
      grid_bar(bcnt, bgen, 128u, (unsigned)t);
    }
  }
}

// ---------------- launcher ----------------
extern "C" void kernel_launch(void* const* d_in, const int* in_sizes, int n_in,
                              void* d_out, int out_size, void* d_ws, size_t ws_size,
                              hipStream_t stream) {
  const float* x = (const float*)d_in[0];
  const float* c0 = (const float*)d_in[1];
  const float* h0 = (const float*)d_in[2];
  const float* Wfx = (const float*)d_in[3];
  const float* bfp = (const float*)d_in[4];
  const float* Wix = (const float*)d_in[5];
  const float* bip = (const float*)d_in[6];
  const float* Wox = (const float*)d_in[7];
  const float* bop = (const float*)d_in[8];
  const float* Wcx = (const float*)d_in[9];
  const float* bcp = (const float*)d_in[10];
  const float* Wfh = (const float*)d_in[11];
  const float* Wih = (const float*)d_in[12];
  const float* Woh = (const float*)d_in[13];
  const float* Wch = (const float*)d_in[14];
  const float* wcf = (const float*)d_in[15];
  const float* wci = (const float*)d_in[16];
  const float* wco = (const float*)d_in[17];
  float* out = (float*)d_out;

  char* ws = (char*)d_ws;
  ushort* xp = (ushort*)(ws + 0);                  // 268,435,456 B
  ushort* WxT = (ushort*)(ws + 268435456ULL);      // 4,194,304 B
  ushort* WhT = (ushort*)(ws + 272629760ULL);      // 8,388,608 B
  float* bias = (float*)(ws + 281018368ULL);       // 16,384 B
  ushort* hA = (ushort*)(ws + 281034752ULL);       // 131,072 B
  ushort* hB = (ushort*)(ws + 281165824ULL);       // 131,072 B
  unsigned* bar = (unsigned*)(ws + 281296896ULL);  // 512 B barrier state
  if (ws_size < 281297408ULL) return;

  const float* wxs[4] = {Wfx, Wix, Wox, Wcx};
  for (int g = 0; g < 4; ++g)
    transpose_cvt<<<dim3(32, 16), dim3(32, 8), 0, stream>>>(
        wxs[g], WxT + (size_t)g * 1024 * 512, 512, 1024);
  const float* whs[4] = {Wfh, Wih, Woh, Wch};
  for (int g = 0; g < 4; ++g)
    transpose_cvt<<<dim3(32, 32), dim3(32, 8), 0, stream>>>(
        whs[g], WhT + (size_t)g * 1024 * 1024, 1024, 1024);
  concat_bias<<<16, 256, 0, stream>>>(bfp, bip, bop, bcp, bias);
  init_h<<<64, 256, 0, stream>>>(h0, hA);
  hipMemsetAsync(bar, 0, 512, stream);
  gemm_xp<<<dim3(32, 256), 256, 0, stream>>>(x, WxT, bias, xp);

  void* args[10];
  args[0] = (void*)&xp;
  args[1] = (void*)&WhT;
  args[2] = (void*)&c0;
  args[3] = (void*)&wcf;
  args[4] = (void*)&wci;
  args[5] = (void*)&wco;
  args[6] = (void*)&hA;
  args[7] = (void*)&hB;
  args[8] = (void*)&out;
  args[9] = (void*)&bar;
  hipLaunchCooperativeKernel((void*)lstm_rec, dim3(256), dim3(256), args, 0, stream);
}

// Round 3
// 6109.037 us; speedup vs baseline: 5.2182x; 1.4406x over previous
//
#include <hip/hip_runtime.h>

typedef __attribute__((ext_vector_type(4))) float f32x4;
typedef __attribute__((ext_vector_type(8))) short short8;
typedef __attribute__((ext_vector_type(8))) unsigned short ushort8;
typedef __attribute__((ext_vector_type(4))) unsigned short ushort4v;
typedef __attribute__((ext_vector_type(4))) unsigned int uint4v;
typedef unsigned short ushort;
typedef unsigned long long u64;

__device__ __forceinline__ ushort f2bf(float f) {
  union { float f; unsigned u; } v; v.f = f;
  unsigned u = v.u;
  return (ushort)((u + 0x7FFFu + ((u >> 16) & 1u)) >> 16);  // RNE
}
__device__ __forceinline__ float bf2f(ushort s) {
  union { unsigned u; float f; } v; v.u = ((unsigned)s) << 16;
  return v.f;
}

// ---------------- prep kernels ----------------

// dst[c][r] = bf16(src[r][c]); src [R][C] f32, dst [C][R] bf16
__global__ void transpose_cvt(const float* __restrict__ src, ushort* __restrict__ dst,
                              int R, int C) {
  __shared__ float tile[32][33];
  int bx = blockIdx.x * 32;  // col in src
  int by = blockIdx.y * 32;  // row in src
  int tx = threadIdx.x, ty = threadIdx.y;
#pragma unroll
  for (int i = 0; i < 32; i += 8)
    tile[ty + i][tx] = src[(size_t)(by + ty + i) * C + bx + tx];
  __syncthreads();
#pragma unroll
  for (int i = 0; i < 32; i += 8)
    dst[(size_t)(bx + ty + i) * R + by + tx] = f2bf(tile[tx][ty + i]);
}

__global__ void concat_bias(const float* a, const float* b, const float* c, const float* d,
                            float* __restrict__ o) {
  int i = blockIdx.x * 256 + threadIdx.x;  // 4096 total
  int g = i >> 10, n = i & 1023;
  float v = (g == 0) ? a[n] : (g == 1) ? b[n] : (g == 2) ? c[n] : d[n];
  o[i] = v;
}

__global__ void init_h(const float* __restrict__ h0, ushort* __restrict__ hA) {
  int i = blockIdx.x * 256 + threadIdx.x;  // 16384 threads * 4 elems
  f32x4 v = *(const f32x4*)(h0 + (size_t)i * 4);
  ushort4v w;
  w.x = f2bf(v.x); w.y = f2bf(v.y); w.z = f2bf(v.z); w.w = f2bf(v.w);
  *(ushort4v*)(hA + (size_t)i * 4) = w;
}

// ---------------- phase 1: xp = x @ Wx + b  (bf16 MFMA) ----------------
// X [32768][512] f32 (row = b*512+t), Bt = WxT [4096][512] bf16, Out [t*64+b][4096] bf16
__global__ __launch_bounds__(256) void gemm_xp(
    const float* __restrict__ X,
    const ushort* __restrict__ Bt,
    const float* __restrict__ bias,
    ushort* __restrict__ Out) {
  __shared__ ushort As[128][40];  // +8 pad kills bank conflicts
  __shared__ ushort Bs[128][40];
  const int tid = threadIdx.x;
  const int lane = tid & 63;
  const int wave = tid >> 6;
  const int wr = wave >> 1, wc = wave & 1;  // 2x2 wave grid, 64x64 each
  const int row0 = blockIdx.y * 128, col0 = blockIdx.x * 128;
  const int l15 = lane & 15, kg = (lane >> 4) * 8;
  f32x4 acc[4][4] = {};
  for (int k0 = 0; k0 < 512; k0 += 32) {
#pragma unroll
    for (int r = 0; r < 2; ++r) {
      int cid = tid + (r << 8);
      int row = cid >> 2, kch = (cid & 3) << 3;
      const float* ap = X + (size_t)(row0 + row) * 512 + k0 + kch;
      f32x4 v0 = *(const f32x4*)ap;
      f32x4 v1 = *(const f32x4*)(ap + 4);
      ushort8 w;
      w[0] = f2bf(v0.x); w[1] = f2bf(v0.y); w[2] = f2bf(v0.z); w[3] = f2bf(v0.w);
      w[4] = f2bf(v1.x); w[5] = f2bf(v1.y); w[6] = f2bf(v1.z); w[7] = f2bf(v1.w);
      *(ushort8*)&As[row][kch] = w;
      uint4v vb = *(const uint4v*)(Bt + (size_t)(col0 + row) * 512 + k0 + kch);
      *(uint4v*)&Bs[row][kch] = vb;
    }
    __syncthreads();
    short8 af[4], bfv[4];
#pragma unroll
    for (int fm = 0; fm < 4; ++fm)
      af[fm] = *(const short8*)&As[wr * 64 + fm * 16 + l15][kg];
#pragma unroll
    for (int fn = 0; fn < 4; ++fn)
      bfv[fn] = *(const short8*)&Bs[wc * 64 + fn * 16 + l15][kg];
#pragma unroll
    for (int fm = 0; fm < 4; ++fm)
#pragma unroll
      for (int fn = 0; fn < 4; ++fn)
        acc[fm][fn] = __builtin_amdgcn_mfma_f32_16x16x32_bf16(af[fm], bfv[fn], acc[fm][fn], 0, 0, 0);
    __syncthreads();
  }
#pragma unroll
  for (int fm = 0; fm < 4; ++fm) {
#pragma unroll
    for (int fn = 0; fn < 4; ++fn) {
#pragma unroll
      for (int r = 0; r < 4; ++r) {
        int gr = row0 + wr * 64 + fm * 16 + ((lane >> 4) << 2) + r;  // D row
        int gc = col0 + wc * 64 + fn * 16 + l15;                     // D col
        int b = gr >> 9, t = gr & 511;                               // gr = b*512 + t
        Out[(size_t)(t * 64 + b) * 4096 + gc] = f2bf(acc[fm][fn][r] + bias[gc]);
      }
    }
  }
}

// ---------------- phase 2: persistent recurrence ----------------
// grid = 256 blocks: bg = blk>>7 (batch half, 32), s = blk&127 (8 units: n = s*8+u)
// block cols c in [0,32): c = g*8 + u  (g = gate f/i/o/c)
// Sync design (no threadfence, no full-L2 maintenance):
//   h stores:  __hip_atomic_store relaxed/agent  -> global_store sc1 (write-through to IF)
//   h loads:   __hip_atomic_load  relaxed/agent  -> global_load sc1  (L2-bypass, reads IF)
//   barrier:   per-wave s_waitcnt vmcnt(0) (stores acked at IF) -> __syncthreads ->
//              tree arrive (16 leaves x 8 blocks, monotonic) -> root -> gen publish -> poll
__global__ __launch_bounds__(256) void lstm_rec(
    const ushort* __restrict__ xp,   // [512*64][4096] bf16, row = t*64+b
    const ushort* __restrict__ whT,  // [4096][1024] bf16 (gate-major cols)
    const float* __restrict__ c0,
    const float* __restrict__ wcf,
    const float* __restrict__ wci,
    const float* __restrict__ wco,
    ushort* __restrict__ hA,         // [64][1024] bf16 ping
    ushort* __restrict__ hB,         // pong
    float* __restrict__ out,         // [64][512][1024] f32
    unsigned* __restrict__ bar) {    // per group: 16 leaves (256B apart) + root + gen
  __shared__ ushort wh_s[32][1032];  // [col][k], +8 pad
  __shared__ ushort h_s[32][1032];   // [batch][k], +8 pad
  __shared__ float G[32][32];        // gate exchange [batch][col]

  const int tid = threadIdx.x;
  const int blk = blockIdx.x;
  const int bg = blk >> 7;
  const int s = blk & 127;
  const int lane = tid & 63;
  const int wave = tid >> 6;
  const int mi = wave >> 1, ni = wave & 1;  // wave tile: batches mi*16.., cols ni*16..

  unsigned* gbar = bar + bg * 2048;              // 8KB per group
  unsigned* leaf = gbar + ((unsigned)(s >> 3)) * 64;  // 16 leaves, 256B apart
  unsigned* rootc = gbar + 1024;                 // own cacheline
  unsigned* gen = gbar + 1056;                   // own cacheline

  // load Wh slice once: block col c -> global col (c>>3)*1024 + s*8 + (c&7)
#pragma unroll
  for (int r = 0; r < 16; ++r) {
    int cid = tid + (r << 8);
    int c = cid >> 7, kc = cid & 127;
    int gcol = ((c >> 3) << 10) + s * 8 + (c & 7);
    uint4v v = *(const uint4v*)(whT + (size_t)gcol * 1024 + kc * 8);
    *(uint4v*)&wh_s[c][kc * 8] = v;
  }

  const int b_l = tid >> 3;  // 0..31
  const int u = tid & 7;     // 0..7
  const int bG = bg * 32 + b_l;
  const int n = s * 8 + u;
  float c_val = c0[(size_t)bG * 1024 + n];
  const float pf = wcf[n], pi = wci[n], po = wco[n];

  const int arow = mi * 16 + (lane & 15);
  const int bcol = ni * 16 + (lane & 15);
  const int kg = (lane >> 4) * 8;

  // prefetch xp for t=0
  const size_t xbase0 = (size_t)bG * 4096 + n;
  ushort px0 = xp[xbase0], px1 = xp[xbase0 + 1024];
  ushort px2 = xp[xbase0 + 2048], px3 = xp[xbase0 + 3072];

  __syncthreads();

  for (int t = 0; t < 512; ++t) {
    const ushort* hprev = (t & 1) ? hB : hA;
    ushort* hnext = (t & 1) ? hA : hB;

    // stage h[bg*32 .. +32][1024] into LDS via sc1 (IF-coherent) 8B loads
    {
      const u64* hsrc = (const u64*)(hprev + (size_t)bg * 32768);
#pragma unroll
      for (int r = 0; r < 32; ++r) {
        u64 v = __hip_atomic_load(hsrc + (size_t)r * 256 + tid,
                                  __ATOMIC_RELAXED, __HIP_MEMORY_SCOPE_AGENT);
        *(u64*)&h_s[r][tid * 4] = v;
      }
    }
    __syncthreads();

    f32x4 acc0 = {0.f, 0.f, 0.f, 0.f}, acc1 = {0.f, 0.f, 0.f, 0.f};
#pragma unroll
    for (int kk = 0; kk < 32; kk += 2) {
      short8 a0 = *(const short8*)&h_s[arow][kk * 32 + kg];
      short8 b0 = *(const short8*)&wh_s[bcol][kk * 32 + kg];
      acc0 = __builtin_amdgcn_mfma_f32_16x16x32_bf16(a0, b0, acc0, 0, 0, 0);
      short8 a1 = *(const short8*)&h_s[arow][kk * 32 + 32 + kg];
      short8 b1 = *(const short8*)&wh_s[bcol][kk * 32 + 32 + kg];
      acc1 = __builtin_amdgcn_mfma_f32_16x16x32_bf16(a1, b1, acc1, 0, 0, 0);
    }
    f32x4 acc = acc0 + acc1;
#pragma unroll
    for (int r = 0; r < 4; ++r) {
      int b = mi * 16 + ((lane >> 4) << 2) + r;
      G[b][ni * 16 + (lane & 15)] = acc[r];
    }
    __syncthreads();

    // elementwise gate update: one (batch, unit) per thread
    float gf = G[b_l][u] + bf2f(px0);
    float gi = G[b_l][8 + u] + bf2f(px1);
    float go = G[b_l][16 + u] + bf2f(px2);
    float gc = G[b_l][24 + u] + bf2f(px3);
    float f = 1.f / (1.f + __expf(-(gf + pf * c_val)));
    float i = 1.f / (1.f + __expf(-(gi + pi * c_val)));
    float ct = 2.f / (1.f + __expf(-2.f * gc)) - 1.f;
    float cn = f * c_val + i * ct;
    float o = 1.f / (1.f + __expf(-(go + po * cn)));
    float h = o * (2.f / (1.f + __expf(-2.f * cn)) - 1.f);
    c_val = cn;
    out[(size_t)(bG * 512 + t) * 1024 + n] = h;  // plain cached store

    if (t < 511) {
      // publish h via sc1 write-through (packed u32, even threads)
      float hx = __shfl_xor(h, 1);
      if ((tid & 1) == 0) {
        unsigned val = (unsigned)f2bf(h) | ((unsigned)f2bf(hx) << 16);
        __hip_atomic_store((unsigned*)hnext + (((size_t)bG << 10) + n) / 2, val,
                           __ATOMIC_RELAXED, __HIP_MEMORY_SCOPE_AGENT);
      }
      asm volatile("s_waitcnt vmcnt(0)" ::: "memory");  // per-wave: h store acked at IF
      __syncthreads();                                  // whole block drained
      if (tid == 0) {
        unsigned r = __hip_atomic_fetch_add(leaf, 1u, __ATOMIC_RELAXED,
                                            __HIP_MEMORY_SCOPE_AGENT);
        if ((r & 7u) == 7u) {  // last of this leaf's 8 blocks
          unsigned q = __hip_atomic_fetch_add(rootc, 1u, __ATOMIC_RELAXED,
                                              __HIP_MEMORY_SCOPE_AGENT);
          if ((q & 15u) == 15u)  // last of 16 leaves
            __hip_atomic_store(gen, (unsigned)t + 1u, __ATOMIC_RELAXED,
                               __HIP_MEMORY_SCOPE_AGENT);
        }
      }
      // prefetch next step's xp while waiting (plain cached loads)
      size_t xb = xbase0 + (size_t)(t + 1) * 262144;  // 64*4096
      px0 = xp[xb]; px1 = xp[xb + 1024]; px2 = xp[xb + 2048]; px3 = xp[xb + 3072];
      if (tid == 0) {
        while (__hip_atomic_load(gen, __ATOMIC_RELAXED, __HIP_MEMORY_SCOPE_AGENT) <
               (unsigned)t + 1u)
          __builtin_amdgcn_s_sleep(1);
      }
      asm volatile("" ::: "memory");
      __syncthreads();
    }
  }
}

// ---------------- launcher ----------------
extern "C" void kernel_launch(void* const* d_in, const int* in_sizes, int n_in,
                              void* d_out, int out_size, void* d_ws, size_t ws_size,
                              hipStream_t stream) {
  const float* x = (const float*)d_in[0];
  const float* c0 = (const float*)d_in[1];
  const float* h0 = (const float*)d_in[2];
  const float* Wfx = (const float*)d_in[3];
  const float* bfp = (const float*)d_in[4];
  const float* Wix = (const float*)d_in[5];
  const float* bip = (const float*)d_in[6];
  const float* Wox = (const float*)d_in[7];
  const float* bop = (const float*)d_in[8];
  const float* Wcx = (const float*)d_in[9];
  const float* bcp = (const float*)d_in[10];
  const float* Wfh = (const float*)d_in[11];
  const float* Wih = (const float*)d_in[12];
  const float* Woh = (const float*)d_in[13];
  const float* Wch = (const float*)d_in[14];
  const float* wcf = (const float*)d_in[15];
  const float* wci = (const float*)d_in[16];
  const float* wco = (const float*)d_in[17];
  float* out = (float*)d_out;

  char* ws = (char*)d_ws;
  ushort* xp = (ushort*)(ws + 0);                  // 268,435,456 B
  ushort* WxT = (ushort*)(ws + 268435456ULL);      // 4,194,304 B
  ushort* WhT = (ushort*)(ws + 272629760ULL);      // 8,388,608 B
  float* bias = (float*)(ws + 281018368ULL);       // 16,384 B
  ushort* hA = (ushort*)(ws + 281034752ULL);       // 131,072 B
  ushort* hB = (ushort*)(ws + 281165824ULL);       // 131,072 B
  unsigned* bar = (unsigned*)(ws + 281296896ULL);  // 16 KB barrier state
  if (ws_size < 281313280ULL) return;

  const float* wxs[4] = {Wfx, Wix, Wox, Wcx};
  for (int g = 0; g < 4; ++g)
    transpose_cvt<<<dim3(32, 16), dim3(32, 8), 0, stream>>>(
        wxs[g], WxT + (size_t)g * 1024 * 512, 512, 1024);
  const float* whs[4] = {Wfh, Wih, Woh, Wch};
  for (int g = 0; g < 4; ++g)
    transpose_cvt<<<dim3(32, 32), dim3(32, 8), 0, stream>>>(
        whs[g], WhT + (size_t)g * 1024 * 1024, 1024, 1024);
  concat_bias<<<16, 256, 0, stream>>>(bfp, bip, bop, bcp, bias);
  init_h<<<64, 256, 0, stream>>>(h0, hA);
  hipMemsetAsync(bar, 0, 16384, stream);
  gemm_xp<<<dim3(32, 256), 256, 0, stream>>>(x, WxT, bias, xp);

  void* args[10];
  args[0] = (void*)&xp;
  args[1] = (void*)&WhT;
  args[2] = (void*)&c0;
  args[3] = (void*)&wcf;
  args[4] = (void*)&wci;
  args[5] = (void*)&wco;
  args[6] = (void*)&hA;
  args[7] = (void*)&hB;
  args[8] = (void*)&out;
  args[9] = (void*)&bar;
  hipLaunchCooperativeKernel((void*)lstm_rec, dim3(256), dim3(256), args, 0, stream);
}

// Round 4
// 4864.173 us; speedup vs baseline: 6.5537x; 1.2559x over previous
//
#include <hip/hip_runtime.h>

typedef __attribute__((ext_vector_type(4))) float f32x4;
typedef __attribute__((ext_vector_type(8))) short short8;
typedef __attribute__((ext_vector_type(8))) unsigned short ushort8;
typedef __attribute__((ext_vector_type(4))) unsigned short ushort4v;
typedef __attribute__((ext_vector_type(4))) unsigned int uint4v;
typedef unsigned short ushort;
typedef unsigned long long u64;

__device__ __forceinline__ ushort f2bf(float f) {
  union { float f; unsigned u; } v; v.f = f;
  unsigned u = v.u;
  return (ushort)((u + 0x7FFFu + ((u >> 16) & 1u)) >> 16);  // RNE
}
__device__ __forceinline__ float bf2f(ushort s) {
  union { unsigned u; float f; } v; v.u = ((unsigned)s) << 16;
  return v.f;
}

// ---------------- prep kernels ----------------

// dst[c][r] = bf16(src[r][c]); src [R][C] f32, dst [C][R] bf16
__global__ void transpose_cvt(const float* __restrict__ src, ushort* __restrict__ dst,
                              int R, int C) {
  __shared__ float tile[32][33];
  int bx = blockIdx.x * 32;  // col in src
  int by = blockIdx.y * 32;  // row in src
  int tx = threadIdx.x, ty = threadIdx.y;
#pragma unroll
  for (int i = 0; i < 32; i += 8)
    tile[ty + i][tx] = src[(size_t)(by + ty + i) * C + bx + tx];
  __syncthreads();
#pragma unroll
  for (int i = 0; i < 32; i += 8)
    dst[(size_t)(bx + ty + i) * R + by + tx] = f2bf(tile[tx][ty + i]);
}

__global__ void concat_bias(const float* a, const float* b, const float* c, const float* d,
                            float* __restrict__ o) {
  int i = blockIdx.x * 256 + threadIdx.x;  // 4096 total
  int g = i >> 10, n = i & 1023;
  float v = (g == 0) ? a[n] : (g == 1) ? b[n] : (g == 2) ? c[n] : d[n];
  o[i] = v;
}

__global__ void init_h(const float* __restrict__ h0, ushort* __restrict__ hA) {
  int i = blockIdx.x * 256 + threadIdx.x;  // 16384 threads * 4 elems
  f32x4 v = *(const f32x4*)(h0 + (size_t)i * 4);
  ushort4v w;
  w.x = f2bf(v.x); w.y = f2bf(v.y); w.z = f2bf(v.z); w.w = f2bf(v.w);
  *(ushort4v*)(hA + (size_t)i * 4) = w;
}

// ---------------- phase 1: xp = x @ Wx + b  (bf16 MFMA) ----------------
// X [32768][512] f32 (row = b*512+t), Bt = WxT [4096][512] bf16, Out [t*64+b][4096] bf16
__global__ __launch_bounds__(256) void gemm_xp(
    const float* __restrict__ X,
    const ushort* __restrict__ Bt,
    const float* __restrict__ bias,
    ushort* __restrict__ Out) {
  __shared__ ushort As[128][40];  // +8 pad kills bank conflicts
  __shared__ ushort Bs[128][40];
  const int tid = threadIdx.x;
  const int lane = tid & 63;
  const int wave = tid >> 6;
  const int wr = wave >> 1, wc = wave & 1;  // 2x2 wave grid, 64x64 each
  const int row0 = blockIdx.y * 128, col0 = blockIdx.x * 128;
  const int l15 = lane & 15, kg = (lane >> 4) * 8;
  f32x4 acc[4][4] = {};
  for (int k0 = 0; k0 < 512; k0 += 32) {
#pragma unroll
    for (int r = 0; r < 2; ++r) {
      int cid = tid + (r << 8);
      int row = cid >> 2, kch = (cid & 3) << 3;
      const float* ap = X + (size_t)(row0 + row) * 512 + k0 + kch;
      f32x4 v0 = *(const f32x4*)ap;
      f32x4 v1 = *(const f32x4*)(ap + 4);
      ushort8 w;
      w[0] = f2bf(v0.x); w[1] = f2bf(v0.y); w[2] = f2bf(v0.z); w[3] = f2bf(v0.w);
      w[4] = f2bf(v1.x); w[5] = f2bf(v1.y); w[6] = f2bf(v1.z); w[7] = f2bf(v1.w);
      *(ushort8*)&As[row][kch] = w;
      uint4v vb = *(const uint4v*)(Bt + (size_t)(col0 + row) * 512 + k0 + kch);
      *(uint4v*)&Bs[row][kch] = vb;
    }
    __syncthreads();
    short8 af[4], bfv[4];
#pragma unroll
    for (int fm = 0; fm < 4; ++fm)
      af[fm] = *(const short8*)&As[wr * 64 + fm * 16 + l15][kg];
#pragma unroll
    for (int fn = 0; fn < 4; ++fn)
      bfv[fn] = *(const short8*)&Bs[wc * 64 + fn * 16 + l15][kg];
#pragma unroll
    for (int fm = 0; fm < 4; ++fm)
#pragma unroll
      for (int fn = 0; fn < 4; ++fn)
        acc[fm][fn] = __builtin_amdgcn_mfma_f32_16x16x32_bf16(af[fm], bfv[fn], acc[fm][fn], 0, 0, 0);
    __syncthreads();
  }
#pragma unroll
  for (int fm = 0; fm < 4; ++fm) {
#pragma unroll
    for (int fn = 0; fn < 4; ++fn) {
#pragma unroll
      for (int r = 0; r < 4; ++r) {
        int gr = row0 + wr * 64 + fm * 16 + ((lane >> 4) << 2) + r;  // D row
        int gc = col0 + wc * 64 + fn * 16 + l15;                     // D col
        int b = gr >> 9, t = gr & 511;                               // gr = b*512 + t
        Out[(size_t)(t * 64 + b) * 4096 + gc] = f2bf(acc[fm][fn][r] + bias[gc]);
      }
    }
  }
}

// ---------------- phase 2: persistent recurrence ----------------
// grid = 256 blocks: bg = blk>>7 (batch half, 32), s = blk&127 (8 units: n = s*8+u)
// Sync: per-block monotone FLAG (plain sc1 store, no RMW). flags[s] = t+1 after
// this block's h stores are vmcnt-acked at IF. Release = all 128 flags >= t+1.
// Wave 0 polls all 128 flags (two 64-lane loads + ballot), publishes per-leaf
// (8-block = 64-unit) readiness to LDS; all waves stage h chunk-by-chunk AS
// LEAVES BECOME READY, overlapping staging with the wait.
__global__ __launch_bounds__(256) void lstm_rec(
    const ushort* __restrict__ xp,   // [512*64][4096] bf16, row = t*64+b
    const ushort* __restrict__ whT,  // [4096][1024] bf16 (gate-major cols)
    const float* __restrict__ c0,
    const float* __restrict__ wcf,
    const float* __restrict__ wci,
    const float* __restrict__ wco,
    ushort* __restrict__ hA,         // [64][1024] bf16 ping
    ushort* __restrict__ hB,         // pong
    float* __restrict__ out,         // [64][512][1024] f32
    unsigned* __restrict__ bar) {    // per group: 128 u32 flags
  __shared__ ushort wh_s[32][1032];  // [col][k], +8 pad
  __shared__ ushort h_s[32][1032];   // [batch][k], +8 pad
  __shared__ float G[32][32];        // gate exchange [batch][col]
  __shared__ unsigned ready_word;    // (t<<16) | leafmask (monotone-tagged)

  const int tid = threadIdx.x;
  const int blk = blockIdx.x;
  const int bg = blk >> 7;
  const int s = blk & 127;
  const int lane = tid & 63;
  const int wave = tid >> 6;
  const int mi = wave >> 1, ni = wave & 1;  // wave tile: batches mi*16.., cols ni*16..

  unsigned* flags = bar + bg * 1024;  // groups 4KB apart

  // load Wh slice once: block col c -> global col (c>>3)*1024 + s*8 + (c&7)
#pragma unroll
  for (int r = 0; r < 16; ++r) {
    int cid = tid + (r << 8);
    int c = cid >> 7, kc = cid & 127;
    int gcol = ((c >> 3) << 10) + s * 8 + (c & 7);
    uint4v v = *(const uint4v*)(whT + (size_t)gcol * 1024 + kc * 8);
    *(uint4v*)&wh_s[c][kc * 8] = v;
  }
  if (tid == 0) ready_word = 0;

  const int b_l = tid >> 3;  // 0..31
  const int u = tid & 7;     // 0..7
  const int bG = bg * 32 + b_l;
  const int n = s * 8 + u;
  float c_val = c0[(size_t)bG * 1024 + n];
  const float pf = wcf[n], pi = wci[n], po = wco[n];

  const int arow = mi * 16 + (lane & 15);
  const int bcol = ni * 16 + (lane & 15);
  const int kg = (lane >> 4) * 8;

  // staging geometry: chunk l = h cols [64l, 64l+64) (leaf l's 8 blocks' units).
  // wave w stages rows [8w, 8w+8): lane -> row 8w+(lane>>3), 16B at u64-idx (lane&7)*2
  const int st_row = (wave << 3) + (lane >> 3);
  const int st_cu = (lane & 7) << 1;

  // prefetch xp for t=0
  const size_t xbase0 = (size_t)bG * 4096 + n;
  ushort px0 = xp[xbase0], px1 = xp[xbase0 + 1024];
  ushort px2 = xp[xbase0 + 2048], px3 = xp[xbase0 + 3072];

  __syncthreads();

  for (int t = 0; t < 512; ++t) {
    const ushort* hprev = (t & 1) ? hB : hA;
    ushort* hnext = (t & 1) ? hA : hB;
    const u64* hp64 = (const u64*)(hprev + (size_t)bg * 32768);

    // ---- stage h chunks as their producer leaves become ready ----
    if (t == 0) {
#pragma unroll
      for (int l = 0; l < 16; ++l) {
        const u64* src = hp64 + ((size_t)st_row << 8) + (l << 4) + st_cu;
        u64 v0 = __hip_atomic_load(src, __ATOMIC_RELAXED, __HIP_MEMORY_SCOPE_AGENT);
        u64 v1 = __hip_atomic_load(src + 1, __ATOMIC_RELAXED, __HIP_MEMORY_SCOPE_AGENT);
        ushort* dst = &h_s[st_row][(l << 6) + (st_cu << 2)];
        *(u64*)dst = v0;
        *(u64*)(dst + 4) = v1;
      }
    } else {
      const unsigned target = (unsigned)t;
      unsigned staged = 0;
      if (wave == 0) {
        for (;;) {
          unsigned fa = __hip_atomic_load(flags + lane, __ATOMIC_RELAXED,
                                          __HIP_MEMORY_SCOPE_AGENT);
          unsigned fb = __hip_atomic_load(flags + 64 + lane, __ATOMIC_RELAXED,
                                          __HIP_MEMORY_SCOPE_AGENT);
          u64 m0 = __ballot(fa >= target);
          u64 m1 = __ballot(fb >= target);
          unsigned lm = 0;
#pragma unroll
          for (int l = 0; l < 8; ++l) {
            if (((m0 >> (l * 8)) & 0xFFull) == 0xFFull) lm |= 1u << l;
            if (((m1 >> (l * 8)) & 0xFFull) == 0xFFull) lm |= 1u << (8 + l);
          }
          if (lane == 0)
            *(volatile unsigned*)&ready_word = (target << 16) | lm;
          unsigned todo = lm & ~staged;
          asm volatile("" ::: "memory");
          while (todo) {
            int l = __ffs(todo) - 1;
            todo &= todo - 1;
            const u64* src = hp64 + ((size_t)st_row << 8) + (l << 4) + st_cu;
            u64 v0 = __hip_atomic_load(src, __ATOMIC_RELAXED, __HIP_MEMORY_SCOPE_AGENT);
            u64 v1 = __hip_atomic_load(src + 1, __ATOMIC_RELAXED, __HIP_MEMORY_SCOPE_AGENT);
            ushort* dst = &h_s[st_row][(l << 6) + (st_cu << 2)];
            *(u64*)dst = v0;
            *(u64*)(dst + 4) = v1;
            staged |= 1u << l;
          }
          if (staged == 0xFFFFu) break;
          __builtin_amdgcn_s_sleep(1);
        }
      } else {
        for (;;) {
          unsigned w = *(volatile unsigned*)&ready_word;
          unsigned lm = ((w >> 16) == target) ? (w & 0xFFFFu) : 0u;
          unsigned todo = lm & ~staged;
          asm volatile("" ::: "memory");
          while (todo) {
            int l = __ffs(todo) - 1;
            todo &= todo - 1;
            const u64* src = hp64 + ((size_t)st_row << 8) + (l << 4) + st_cu;
            u64 v0 = __hip_atomic_load(src, __ATOMIC_RELAXED, __HIP_MEMORY_SCOPE_AGENT);
            u64 v1 = __hip_atomic_load(src + 1, __ATOMIC_RELAXED, __HIP_MEMORY_SCOPE_AGENT);
            ushort* dst = &h_s[st_row][(l << 6) + (st_cu << 2)];
            *(u64*)dst = v0;
            *(u64*)(dst + 4) = v1;
            staged |= 1u << l;
          }
          if (staged == 0xFFFFu) break;
          __builtin_amdgcn_s_sleep(1);
        }
      }
    }
    __syncthreads();

    // ---- h @ Wh (MFMA over K=1024) ----
    f32x4 acc0 = {0.f, 0.f, 0.f, 0.f}, acc1 = {0.f, 0.f, 0.f, 0.f};
#pragma unroll
    for (int kk = 0; kk < 32; kk += 2) {
      short8 a0 = *(const short8*)&h_s[arow][kk * 32 + kg];
      short8 b0 = *(const short8*)&wh_s[bcol][kk * 32 + kg];
      acc0 = __builtin_amdgcn_mfma_f32_16x16x32_bf16(a0, b0, acc0, 0, 0, 0);
      short8 a1 = *(const short8*)&h_s[arow][kk * 32 + 32 + kg];
      short8 b1 = *(const short8*)&wh_s[bcol][kk * 32 + 32 + kg];
      acc1 = __builtin_amdgcn_mfma_f32_16x16x32_bf16(a1, b1, acc1, 0, 0, 0);
    }
    f32x4 acc = acc0 + acc1;
#pragma unroll
    for (int r = 0; r < 4; ++r) {
      int b = mi * 16 + ((lane >> 4) << 2) + r;
      G[b][ni * 16 + (lane & 15)] = acc[r];
    }
    __syncthreads();

    // ---- elementwise gate update: one (batch, unit) per thread ----
    float gf = G[b_l][u] + bf2f(px0);
    float gi = G[b_l][8 + u] + bf2f(px1);
    float go = G[b_l][16 + u] + bf2f(px2);
    float gc = G[b_l][24 + u] + bf2f(px3);
    float f = 1.f / (1.f + __expf(-(gf + pf * c_val)));
    float i = 1.f / (1.f + __expf(-(gi + pi * c_val)));
    float ct = 2.f / (1.f + __expf(-2.f * gc)) - 1.f;
    float cn = f * c_val + i * ct;
    float o = 1.f / (1.f + __expf(-(go + po * cn)));
    float h = o * (2.f / (1.f + __expf(-2.f * cn)) - 1.f);
    c_val = cn;
    out[(size_t)(bG * 512 + t) * 1024 + n] = h;  // plain cached store

    if (t < 511) {
      // publish h via sc1 write-through (packed u32, even threads)
      float hx = __shfl_xor(h, 1);
      if ((tid & 1) == 0) {
        unsigned val = (unsigned)f2bf(h) | ((unsigned)f2bf(hx) << 16);
        __hip_atomic_store((unsigned*)hnext + (((size_t)bG << 10) + n) / 2, val,
                           __ATOMIC_RELAXED, __HIP_MEMORY_SCOPE_AGENT);
      }
      asm volatile("s_waitcnt vmcnt(0)" ::: "memory");  // h stores acked at IF
      __syncthreads();                                  // all waves drained
      if (tid == 0)  // fire-and-forget arrival: monotone flag store, no RMW
        __hip_atomic_store(flags + s, (unsigned)t + 1u, __ATOMIC_RELAXED,
                           __HIP_MEMORY_SCOPE_AGENT);
      // prefetch next step's xp (plain cached); completes during the poll
      size_t xb = xbase0 + (size_t)(t + 1) * 262144;  // 64*4096
      px0 = xp[xb]; px1 = xp[xb + 1024]; px2 = xp[xb + 2048]; px3 = xp[xb + 3072];
    }
  }
}

// ---------------- launcher ----------------
extern "C" void kernel_launch(void* const* d_in, const int* in_sizes, int n_in,
                              void* d_out, int out_size, void* d_ws, size_t ws_size,
                              hipStream_t stream) {
  const float* x = (const float*)d_in[0];
  const float* c0 = (const float*)d_in[1];
  const float* h0 = (const float*)d_in[2];
  const float* Wfx = (const float*)d_in[3];
  const float* bfp = (const float*)d_in[4];
  const float* Wix = (const float*)d_in[5];
  const float* bip = (const float*)d_in[6];
  const float* Wox = (const float*)d_in[7];
  const float* bop = (const float*)d_in[8];
  const float* Wcx = (const float*)d_in[9];
  const float* bcp = (const float*)d_in[10];
  const float* Wfh = (const float*)d_in[11];
  const float* Wih = (const float*)d_in[12];
  const float* Woh = (const float*)d_in[13];
  const float* Wch = (const float*)d_in[14];
  const float* wcf = (const float*)d_in[15];
  const float* wci = (const float*)d_in[16];
  const float* wco = (const float*)d_in[17];
  float* out = (float*)d_out;

  char* ws = (char*)d_ws;
  ushort* xp = (ushort*)(ws + 0);                  // 268,435,456 B
  ushort* WxT = (ushort*)(ws + 268435456ULL);      // 4,194,304 B
  ushort* WhT = (ushort*)(ws + 272629760ULL);      // 8,388,608 B
  float* bias = (float*)(ws + 281018368ULL);       // 16,384 B
  ushort* hA = (ushort*)(ws + 281034752ULL);       // 131,072 B
  ushort* hB = (ushort*)(ws + 281165824ULL);       // 131,072 B
  unsigned* bar = (unsigned*)(ws + 281296896ULL);  // 16 KB flag state
  if (ws_size < 281313280ULL) return;

  const float* wxs[4] = {Wfx, Wix, Wox, Wcx};
  for (int g = 0; g < 4; ++g)
    transpose_cvt<<<dim3(32, 16), dim3(32, 8), 0, stream>>>(
        wxs[g], WxT + (size_t)g * 1024 * 512, 512, 1024);
  const float* whs[4] = {Wfh, Wih, Woh, Wch};
  for (int g = 0; g < 4; ++g)
    transpose_cvt<<<dim3(32, 32), dim3(32, 8), 0, stream>>>(
        whs[g], WhT + (size_t)g * 1024 * 1024, 1024, 1024);
  concat_bias<<<16, 256, 0, stream>>>(bfp, bip, bop, bcp, bias);
  init_h<<<64, 256, 0, stream>>>(h0, hA);
  hipMemsetAsync(bar, 0, 16384, stream);
  gemm_xp<<<dim3(32, 256), 256, 0, stream>>>(x, WxT, bias, xp);

  void* args[10];
  args[0] = (void*)&xp;
  args[1] = (void*)&WhT;
  args[2] = (void*)&c0;
  args[3] = (void*)&wcf;
  args[4] = (void*)&wci;
  args[5] = (void*)&wco;
  args[6] = (void*)&hA;
  args[7] = (void*)&hB;
  args[8] = (void*)&out;
  args[9] = (void*)&bar;
  hipLaunchCooperativeKernel((void*)lstm_rec, dim3(256), dim3(256), args, 0, stream);
}

// Round 5
// 4414.185 us; speedup vs baseline: 7.2218x; 1.1019x over previous
//
#include <hip/hip_runtime.h>

typedef __attribute__((ext_vector_type(4))) float f32x4;
typedef __attribute__((ext_vector_type(8))) short short8;
typedef __attribute__((ext_vector_type(8))) unsigned short ushort8;
typedef __attribute__((ext_vector_type(4))) unsigned short ushort4v;
typedef __attribute__((ext_vector_type(4))) unsigned int uint4v;
typedef unsigned short ushort;
typedef unsigned long long u64;

__device__ __forceinline__ ushort f2bf(float f) {
  union { float f; unsigned u; } v; v.f = f;
  unsigned u = v.u;
  return (ushort)((u + 0x7FFFu + ((u >> 16) & 1u)) >> 16);  // RNE
}
__device__ __forceinline__ float bf2f(ushort s) {
  union { unsigned u; float f; } v; v.u = ((unsigned)s) << 16;
  return v.f;
}

// ---------------- prep kernels ----------------

// dst[c][r] = bf16(src[r][c]); src [R][C] f32, dst [C][R] bf16
__global__ void transpose_cvt(const float* __restrict__ src, ushort* __restrict__ dst,
                              int R, int C) {
  __shared__ float tile[32][33];
  int bx = blockIdx.x * 32;  // col in src
  int by = blockIdx.y * 32;  // row in src
  int tx = threadIdx.x, ty = threadIdx.y;
#pragma unroll
  for (int i = 0; i < 32; i += 8)
    tile[ty + i][tx] = src[(size_t)(by + ty + i) * C + bx + tx];
  __syncthreads();
#pragma unroll
  for (int i = 0; i < 32; i += 8)
    dst[(size_t)(bx + ty + i) * R + by + tx] = f2bf(tile[tx][ty + i]);
}

__global__ void concat_bias(const float* a, const float* b, const float* c, const float* d,
                            float* __restrict__ o) {
  int i = blockIdx.x * 256 + threadIdx.x;  // 4096 total
  int g = i >> 10, n = i & 1023;
  float v = (g == 0) ? a[n] : (g == 1) ? b[n] : (g == 2) ? c[n] : d[n];
  o[i] = v;
}

__global__ void init_h(const float* __restrict__ h0, ushort* __restrict__ hA) {
  int i = blockIdx.x * 256 + threadIdx.x;  // 16384 threads * 4 elems
  f32x4 v = *(const f32x4*)(h0 + (size_t)i * 4);
  ushort4v w;
  w.x = f2bf(v.x); w.y = f2bf(v.y); w.z = f2bf(v.z); w.w = f2bf(v.w);
  *(ushort4v*)(hA + (size_t)i * 4) = w;
}

// ---------------- phase 1: xp = x @ Wx + b  (bf16 MFMA) ----------------
// X [32768][512] f32 (row = b*512+t), Bt = WxT [4096][512] bf16, Out [t*64+b][4096] bf16
__global__ __launch_bounds__(256) void gemm_xp(
    const float* __restrict__ X,
    const ushort* __restrict__ Bt,
    const float* __restrict__ bias,
    ushort* __restrict__ Out) {
  __shared__ ushort As[128][40];  // +8 pad kills bank conflicts
  __shared__ ushort Bs[128][40];
  const int tid = threadIdx.x;
  const int lane = tid & 63;
  const int wave = tid >> 6;
  const int wr = wave >> 1, wc = wave & 1;  // 2x2 wave grid, 64x64 each
  const int row0 = blockIdx.y * 128, col0 = blockIdx.x * 128;
  const int l15 = lane & 15, kg = (lane >> 4) * 8;
  f32x4 acc[4][4] = {};
  for (int k0 = 0; k0 < 512; k0 += 32) {
#pragma unroll
    for (int r = 0; r < 2; ++r) {
      int cid = tid + (r << 8);
      int row = cid >> 2, kch = (cid & 3) << 3;
      const float* ap = X + (size_t)(row0 + row) * 512 + k0 + kch;
      f32x4 v0 = *(const f32x4*)ap;
      f32x4 v1 = *(const f32x4*)(ap + 4);
      ushort8 w;
      w[0] = f2bf(v0.x); w[1] = f2bf(v0.y); w[2] = f2bf(v0.z); w[3] = f2bf(v0.w);
      w[4] = f2bf(v1.x); w[5] = f2bf(v1.y); w[6] = f2bf(v1.z); w[7] = f2bf(v1.w);
      *(ushort8*)&As[row][kch] = w;
      uint4v vb = *(const uint4v*)(Bt + (size_t)(col0 + row) * 512 + k0 + kch);
      *(uint4v*)&Bs[row][kch] = vb;
    }
    __syncthreads();
    short8 af[4], bfv[4];
#pragma unroll
    for (int fm = 0; fm < 4; ++fm)
      af[fm] = *(const short8*)&As[wr * 64 + fm * 16 + l15][kg];
#pragma unroll
    for (int fn = 0; fn < 4; ++fn)
      bfv[fn] = *(const short8*)&Bs[wc * 64 + fn * 16 + l15][kg];
#pragma unroll
    for (int fm = 0; fm < 4; ++fm)
#pragma unroll
      for (int fn = 0; fn < 4; ++fn)
        acc[fm][fn] = __builtin_amdgcn_mfma_f32_16x16x32_bf16(af[fm], bfv[fn], acc[fm][fn], 0, 0, 0);
    __syncthreads();
  }
#pragma unroll
  for (int fm = 0; fm < 4; ++fm) {
#pragma unroll
    for (int fn = 0; fn < 4; ++fn) {
#pragma unroll
      for (int r = 0; r < 4; ++r) {
        int gr = row0 + wr * 64 + fm * 16 + ((lane >> 4) << 2) + r;  // D row
        int gc = col0 + wc * 64 + fn * 16 + l15;                     // D col
        int b = gr >> 9, t = gr & 511;                               // gr = b*512 + t
        Out[(size_t)(t * 64 + b) * 4096 + gc] = f2bf(acc[fm][fn][r] + bias[gc]);
      }
    }
  }
}

// ---------------- phase 2: persistent recurrence ----------------
// grid = 256 blocks: bg = blk>>7 (batch half, 32), s = blk&127 (8 units: n = s*8+u)
// Per-wave K-slice pipeline: wave w owns K-window [256w, 256w+256) = chunks
// 4w..4w+3 (chunk l = h units [64l,64l+64), produced by blocks 8l..8l+7).
// Wave polls ITS 32 producer flags (1 sc1 load/iter), stages each ready chunk
// into its PRIVATE h_s column window, immediately MFMAs it (2 k-steps x 4
// tiles), accumulating a partial gate-sum. No cross-wave sync until the
// G-partial exchange. Then: gates, h publish (sc1), vmcnt(0), sync, flag.
__global__ __launch_bounds__(256) void lstm_rec(
    const ushort* __restrict__ xp,   // [512*64][4096] bf16, row = t*64+b
    const ushort* __restrict__ whT,  // [4096][1024] bf16 (gate-major cols)
    const float* __restrict__ c0,
    const float* __restrict__ wcf,
    const float* __restrict__ wci,
    const float* __restrict__ wco,
    ushort* __restrict__ hA,         // [64][1024] bf16 ping
    ushort* __restrict__ hB,         // pong
    float* __restrict__ out,         // [64][512][1024] f32
    unsigned* __restrict__ bar) {    // per group: 128 u32 flags (monotone)
  __shared__ ushort wh_s[32][1032];  // [col][k], +8 pad
  __shared__ ushort h_s[32][1032];   // [batch][k], +8 pad
  __shared__ float G[4][32][32];     // per-wave partial gates [w][batch][col]

  const int tid = threadIdx.x;
  const int blk = blockIdx.x;
  const int bg = blk >> 7;
  const int s = blk & 127;
  const int lane = tid & 63;
  const int wave = tid >> 6;

  unsigned* flags = bar + bg * 1024;  // groups 4KB apart

  // load Wh slice once: block col c -> global col (c>>3)*1024 + s*8 + (c&7)
#pragma unroll
  for (int r = 0; r < 16; ++r) {
    int cid = tid + (r << 8);
    int c = cid >> 7, kc = cid & 127;
    int gcol = ((c >> 3) << 10) + s * 8 + (c & 7);
    uint4v v = *(const uint4v*)(whT + (size_t)gcol * 1024 + kc * 8);
    *(uint4v*)&wh_s[c][kc * 8] = v;
  }

  const int b_l = tid >> 3;  // 0..31
  const int u = tid & 7;     // 0..7
  const int bG = bg * 32 + b_l;
  const int n = s * 8 + u;
  float c_val = c0[(size_t)bG * 1024 + n];
  const float pf = wcf[n], pi = wci[n], po = wco[n];

  const int l15 = lane & 15;
  const int kg = (lane >> 4) * 8;
  const int st_row = lane >> 1;          // staging: 2 lanes per batch-row
  const int st_half = lane & 1;          // each lane: 64B = 8 u64

  // prefetch xp for t=0
  const size_t xbase0 = (size_t)bG * 4096 + n;
  ushort px0 = xp[xbase0], px1 = xp[xbase0 + 1024];
  ushort px2 = xp[xbase0 + 2048], px3 = xp[xbase0 + 3072];

  __syncthreads();

  for (int t = 0; t < 512; ++t) {
    const ushort* hprev = (t & 1) ? hB : hA;
    ushort* hnext = (t & 1) ? hA : hB;
    const u64* hp64 = (const u64*)(hprev + (size_t)bg * 32768);

    // ---- per-wave: poll own producer flags, stage+MFMA chunks as ready ----
    f32x4 a00 = {}, a01 = {}, a10 = {}, a11 = {};
    {
      const unsigned target = (unsigned)t;
      unsigned staged = 0;
      for (;;) {
        unsigned fv = (lane < 32)
            ? __hip_atomic_load(flags + (wave << 5) + lane, __ATOMIC_RELAXED,
                                __HIP_MEMORY_SCOPE_AGENT)
            : target;
        u64 m = __ballot(fv >= target);
        unsigned rm = 0;
#pragma unroll
        for (int c = 0; c < 4; ++c)
          if (((m >> (c * 8)) & 0xFFull) == 0xFFull) rm |= 1u << c;
        unsigned todo = rm & ~staged;
        while (todo) {
          int c = __ffs(todo) - 1;
          todo &= todo - 1;
          const int l = (wave << 2) + c;  // chunk index; k0 = 64*l
          // stage: 32 rows x 64 units; lane -> row st_row, 8 u64
          const u64* src = hp64 + ((size_t)st_row << 8) + (l << 4) + (st_half << 3);
          ushort* dst = &h_s[st_row][(l << 6) + (st_half << 5)];
          u64 v0 = __hip_atomic_load(src + 0, __ATOMIC_RELAXED, __HIP_MEMORY_SCOPE_AGENT);
          u64 v1 = __hip_atomic_load(src + 1, __ATOMIC_RELAXED, __HIP_MEMORY_SCOPE_AGENT);
          u64 v2 = __hip_atomic_load(src + 2, __ATOMIC_RELAXED, __HIP_MEMORY_SCOPE_AGENT);
          u64 v3 = __hip_atomic_load(src + 3, __ATOMIC_RELAXED, __HIP_MEMORY_SCOPE_AGENT);
          u64 v4 = __hip_atomic_load(src + 4, __ATOMIC_RELAXED, __HIP_MEMORY_SCOPE_AGENT);
          u64 v5 = __hip_atomic_load(src + 5, __ATOMIC_RELAXED, __HIP_MEMORY_SCOPE_AGENT);
          u64 v6 = __hip_atomic_load(src + 6, __ATOMIC_RELAXED, __HIP_MEMORY_SCOPE_AGENT);
          u64 v7 = __hip_atomic_load(src + 7, __ATOMIC_RELAXED, __HIP_MEMORY_SCOPE_AGENT);
          *(u64*)(dst + 0)  = v0; *(u64*)(dst + 4)  = v1;
          *(u64*)(dst + 8)  = v2; *(u64*)(dst + 12) = v3;
          *(u64*)(dst + 16) = v4; *(u64*)(dst + 20) = v5;
          *(u64*)(dst + 24) = v6; *(u64*)(dst + 28) = v7;
          // MFMA this chunk's K-slice (2 k-steps x 4 tiles)
#pragma unroll
          for (int kk = 0; kk < 2; ++kk) {
            const int ko = (l << 6) + (kk << 5) + kg;
            short8 fa0 = *(const short8*)&h_s[l15][ko];
            short8 fa1 = *(const short8*)&h_s[16 + l15][ko];
            short8 fb0 = *(const short8*)&wh_s[l15][ko];
            short8 fb1 = *(const short8*)&wh_s[16 + l15][ko];
            a00 = __builtin_amdgcn_mfma_f32_16x16x32_bf16(fa0, fb0, a00, 0, 0, 0);
            a01 = __builtin_amdgcn_mfma_f32_16x16x32_bf16(fa0, fb1, a01, 0, 0, 0);
            a10 = __builtin_amdgcn_mfma_f32_16x16x32_bf16(fa1, fb0, a10, 0, 0, 0);
            a11 = __builtin_amdgcn_mfma_f32_16x16x32_bf16(fa1, fb1, a11, 0, 0, 0);
          }
          staged |= 1u << c;
        }
        if (staged == 0xFu) break;
        __builtin_amdgcn_s_sleep(1);
      }
    }

    // ---- write per-wave partial gates ----
#pragma unroll
    for (int r = 0; r < 4; ++r) {
      const int rr = ((lane >> 4) << 2) + r;
      G[wave][rr][l15]           = a00[r];
      G[wave][rr][16 + l15]      = a01[r];
      G[wave][16 + rr][l15]      = a10[r];
      G[wave][16 + rr][16 + l15] = a11[r];
    }
    __syncthreads();  // sync#1: G partials ready

    // ---- elementwise gate update: one (batch, unit) per thread ----
    float gf = (G[0][b_l][u]      + G[1][b_l][u])      + (G[2][b_l][u]      + G[3][b_l][u])      + bf2f(px0);
    float gi = (G[0][b_l][8 + u]  + G[1][b_l][8 + u])  + (G[2][b_l][8 + u]  + G[3][b_l][8 + u])  + bf2f(px1);
    float go = (G[0][b_l][16 + u] + G[1][b_l][16 + u]) + (G[2][b_l][16 + u] + G[3][b_l][16 + u]) + bf2f(px2);
    float gc = (G[0][b_l][24 + u] + G[1][b_l][24 + u]) + (G[2][b_l][24 + u] + G[3][b_l][24 + u]) + bf2f(px3);
    float f = 1.f / (1.f + __expf(-(gf + pf * c_val)));
    float i = 1.f / (1.f + __expf(-(gi + pi * c_val)));
    float ct = 2.f / (1.f + __expf(-2.f * gc)) - 1.f;
    float cn = f * c_val + i * ct;
    float o = 1.f / (1.f + __expf(-(go + po * cn)));
    float h = o * (2.f / (1.f + __expf(-2.f * cn)) - 1.f);
    c_val = cn;

    if (t < 511) {
      // publish h via sc1 write-through (packed u32, even threads)
      float hx = __shfl_xor(h, 1);
      if ((tid & 1) == 0) {
        unsigned val = (unsigned)f2bf(h) | ((unsigned)f2bf(hx) << 16);
        __hip_atomic_store((unsigned*)hnext + (((size_t)bG << 10) + n) / 2, val,
                           __ATOMIC_RELAXED, __HIP_MEMORY_SCOPE_AGENT);
      }
      asm volatile("s_waitcnt vmcnt(0)" ::: "memory");  // h stores acked at IF
      __syncthreads();  // sync#2: all waves drained; also guards G(t) reads
      if (tid == 0)     // fire-and-forget monotone arrival flag
        __hip_atomic_store(flags + s, (unsigned)t + 1u, __ATOMIC_RELAXED,
                           __HIP_MEMORY_SCOPE_AGENT);
      // prefetch next step's xp (plain cached); completes during next poll
      size_t xb = xbase0 + (size_t)(t + 1) * 262144;  // 64*4096
      px0 = xp[xb]; px1 = xp[xb + 1024]; px2 = xp[xb + 2048]; px3 = xp[xb + 3072];
    }
    // out store off the critical path (after flag publish)
    out[(size_t)(bG * 512 + t) * 1024 + n] = h;
  }
}

// ---------------- launcher ----------------
extern "C" void kernel_launch(void* const* d_in, const int* in_sizes, int n_in,
                              void* d_out, int out_size, void* d_ws, size_t ws_size,
                              hipStream_t stream) {
  const float* x = (const float*)d_in[0];
  const float* c0 = (const float*)d_in[1];
  const float* h0 = (const float*)d_in[2];
  const float* Wfx = (const float*)d_in[3];
  const float* bfp = (const float*)d_in[4];
  const float* Wix = (const float*)d_in[5];
  const float* bip = (const float*)d_in[6];
  const float* Wox = (const float*)d_in[7];
  const float* bop = (const float*)d_in[8];
  const float* Wcx = (const float*)d_in[9];
  const float* bcp = (const float*)d_in[10];
  const float* Wfh = (const float*)d_in[11];
  const float* Wih = (const float*)d_in[12];
  const float* Woh = (const float*)d_in[13];
  const float* Wch = (const float*)d_in[14];
  const float* wcf = (const float*)d_in[15];
  const float* wci = (const float*)d_in[16];
  const float* wco = (const float*)d_in[17];
  float* out = (float*)d_out;

  char* ws = (char*)d_ws;
  ushort* xp = (ushort*)(ws + 0);                  // 268,435,456 B
  ushort* WxT = (ushort*)(ws + 268435456ULL);      // 4,194,304 B
  ushort* WhT = (ushort*)(ws + 272629760ULL);      // 8,388,608 B
  float* bias = (float*)(ws + 281018368ULL);       // 16,384 B
  ushort* hA = (ushort*)(ws + 281034752ULL);       // 131,072 B
  ushort* hB = (ushort*)(ws + 281165824ULL);       // 131,072 B
  unsigned* bar = (unsigned*)(ws + 281296896ULL);  // 16 KB flag state
  if (ws_size < 281313280ULL) return;

  const float* wxs[4] = {Wfx, Wix, Wox, Wcx};
  for (int g = 0; g < 4; ++g)
    transpose_cvt<<<dim3(32, 16), dim3(32, 8), 0, stream>>>(
        wxs[g], WxT + (size_t)g * 1024 * 512, 512, 1024);
  const float* whs[4] = {Wfh, Wih, Woh, Wch};
  for (int g = 0; g < 4; ++g)
    transpose_cvt<<<dim3(32, 32), dim3(32, 8), 0, stream>>>(
        whs[g], WhT + (size_t)g * 1024 * 1024, 1024, 1024);
  concat_bias<<<16, 256, 0, stream>>>(bfp, bip, bop, bcp, bias);
  init_h<<<64, 256, 0, stream>>>(h0, hA);
  hipMemsetAsync(bar, 0, 16384, stream);
  gemm_xp<<<dim3(32, 256), 256, 0, stream>>>(x, WxT, bias, xp);

  void* args[10];
  args[0] = (void*)&xp;
  args[1] = (void*)&WhT;
  args[2] = (void*)&c0;
  args[3] = (void*)&wcf;
  args[4] = (void*)&wci;
  args[5] = (void*)&wco;
  args[6] = (void*)&hA;
  args[7] = (void*)&hB;
  args[8] = (void*)&out;
  args[9] = (void*)&bar;
  hipLaunchCooperativeKernel((void*)lstm_rec, dim3(256), dim3(256), args, 0, stream);
}

// Round 6
// 3232.714 us; speedup vs baseline: 9.8611x; 1.3655x over previous
//
#include <hip/hip_runtime.h>

typedef __attribute__((ext_vector_type(4))) float f32x4;
typedef __attribute__((ext_vector_type(8))) short short8;
typedef __attribute__((ext_vector_type(8))) unsigned short ushort8;
typedef __attribute__((ext_vector_type(4))) unsigned short ushort4v;
typedef __attribute__((ext_vector_type(4))) unsigned int uint4v;
typedef unsigned short ushort;
typedef unsigned long long u64;

__device__ __forceinline__ ushort f2bf(float f) {
  union { float f; unsigned u; } v; v.f = f;
  unsigned u = v.u;
  return (ushort)((u + 0x7FFFu + ((u >> 16) & 1u)) >> 16);  // RNE
}
__device__ __forceinline__ float bf2f(ushort s) {
  union { unsigned u; float f; } v; v.u = ((unsigned)s) << 16;
  return v.f;
}

// raw LDS-only block barrier: no vmem drain (h publish stores stay in flight)
#define LGKM_BAR() asm volatile("s_waitcnt lgkmcnt(0)\n\ts_barrier" ::: "memory")

// ---------------- prep kernels ----------------

// dst[c][r] = bf16(src[r][c]); src [R][C] f32, dst [C][R] bf16
__global__ void transpose_cvt(const float* __restrict__ src, ushort* __restrict__ dst,
                              int R, int C) {
  __shared__ float tile[32][33];
  int bx = blockIdx.x * 32;  // col in src
  int by = blockIdx.y * 32;  // row in src
  int tx = threadIdx.x, ty = threadIdx.y;
#pragma unroll
  for (int i = 0; i < 32; i += 8)
    tile[ty + i][tx] = src[(size_t)(by + ty + i) * C + bx + tx];
  __syncthreads();
#pragma unroll
  for (int i = 0; i < 32; i += 8)
    dst[(size_t)(bx + ty + i) * R + by + tx] = f2bf(tile[tx][ty + i]);
}

__global__ void concat_bias(const float* a, const float* b, const float* c, const float* d,
                            float* __restrict__ o) {
  int i = blockIdx.x * 256 + threadIdx.x;  // 4096 total
  int g = i >> 10, n = i & 1023;
  float v = (g == 0) ? a[n] : (g == 1) ? b[n] : (g == 2) ? c[n] : d[n];
  o[i] = v;
}

// tagged h0: slot i = (tag 0 << 32) | bf16(h0[2i+1])<<16 | bf16(h0[2i])
__global__ void init_tagged(const float* __restrict__ h0, u64* __restrict__ tb0) {
  int i = blockIdx.x * 256 + threadIdx.x;  // 32768 slots
  float a = h0[(size_t)2 * i], b = h0[(size_t)2 * i + 1];
  tb0[i] = (u64)((unsigned)f2bf(a) | ((unsigned)f2bf(b) << 16));
}

// ---------------- phase 1: xp = x @ Wx + b  (bf16 MFMA) ----------------
// X [32768][512] f32 (row = b*512+t), Bt = WxT [4096][512] bf16, Out [t*64+b][4096] bf16
__global__ __launch_bounds__(256) void gemm_xp(
    const float* __restrict__ X,
    const ushort* __restrict__ Bt,
    const float* __restrict__ bias,
    ushort* __restrict__ Out) {
  __shared__ ushort As[128][40];  // +8 pad kills bank conflicts
  __shared__ ushort Bs[128][40];
  const int tid = threadIdx.x;
  const int lane = tid & 63;
  const int wave = tid >> 6;
  const int wr = wave >> 1, wc = wave & 1;  // 2x2 wave grid, 64x64 each
  const int row0 = blockIdx.y * 128, col0 = blockIdx.x * 128;
  const int l15 = lane & 15, kg = (lane >> 4) * 8;
  f32x4 acc[4][4] = {};
  for (int k0 = 0; k0 < 512; k0 += 32) {
#pragma unroll
    for (int r = 0; r < 2; ++r) {
      int cid = tid + (r << 8);
      int row = cid >> 2, kch = (cid & 3) << 3;
      const float* ap = X + (size_t)(row0 + row) * 512 + k0 + kch;
      f32x4 v0 = *(const f32x4*)ap;
      f32x4 v1 = *(const f32x4*)(ap + 4);
      ushort8 w;
      w[0] = f2bf(v0.x); w[1] = f2bf(v0.y); w[2] = f2bf(v0.z); w[3] = f2bf(v0.w);
      w[4] = f2bf(v1.x); w[5] = f2bf(v1.y); w[6] = f2bf(v1.z); w[7] = f2bf(v1.w);
      *(ushort8*)&As[row][kch] = w;
      uint4v vb = *(const uint4v*)(Bt + (size_t)(col0 + row) * 512 + k0 + kch);
      *(uint4v*)&Bs[row][kch] = vb;
    }
    __syncthreads();
    short8 af[4], bfv[4];
#pragma unroll
    for (int fm = 0; fm < 4; ++fm)
      af[fm] = *(const short8*)&As[wr * 64 + fm * 16 + l15][kg];
#pragma unroll
    for (int fn = 0; fn < 4; ++fn)
      bfv[fn] = *(const short8*)&Bs[wc * 64 + fn * 16 + l15][kg];
#pragma unroll
    for (int fm = 0; fm < 4; ++fm)
#pragma unroll
      for (int fn = 0; fn < 4; ++fn)
        acc[fm][fn] = __builtin_amdgcn_mfma_f32_16x16x32_bf16(af[fm], bfv[fn], acc[fm][fn], 0, 0, 0);
    __syncthreads();
  }
#pragma unroll
  for (int fm = 0; fm < 4; ++fm) {
#pragma unroll
    for (int fn = 0; fn < 4; ++fn) {
#pragma unroll
      for (int r = 0; r < 4; ++r) {
        int gr = row0 + wr * 64 + fm * 16 + ((lane >> 4) << 2) + r;  // D row
        int gc = col0 + wc * 64 + fn * 16 + l15;                     // D col
        int b = gr >> 9, t = gr & 511;                               // gr = b*512 + t
        Out[(size_t)(t * 64 + b) * 4096 + gc] = f2bf(acc[fm][fn][r] + bias[gc]);
      }
    }
  }
}

// ---------------- phase 2: persistent recurrence, tag-embedded h ----------------
// grid = 256 blocks: bg = blk>>7 (batch half, 32), s = blk&127 (8 units: n = s*8+u)
// h exchange: tb[parity][64 batch][512 slots] u64; slot j = (tag<<32) | units(2j,2j+1).
// Producer: ONE fire-and-forget sc1 store per even thread (data+flag fused). No
// vmcnt ack, no flag, no barrier on the publish path. Consumer: wave w polls its
// K-window slots directly; tag==t load IS the data. Parity buffers + monotone
// tags make overwrite transitively safe (publish t+1 requires staging all t,
// which requires all blocks published t, which requires all staged t-1).
__global__ __launch_bounds__(256) void lstm_rec(
    const ushort* __restrict__ xp,   // [512*64][4096] bf16, row = t*64+b
    const ushort* __restrict__ whT,  // [4096][1024] bf16 (gate-major cols)
    const float* __restrict__ c0,
    const float* __restrict__ wcf,
    const float* __restrict__ wci,
    const float* __restrict__ wco,
    u64* __restrict__ tb,            // [2][64][512] tagged slots
    float* __restrict__ out) {       // [64][512][1024] f32
  __shared__ ushort wh_s[32][1032];  // [col][k], +8 pad
  __shared__ ushort h_s[32][1032];   // [batch][k], +8 pad
  __shared__ float G[4][32][32];     // per-wave partial gates [w][batch][col]

  const int tid = threadIdx.x;
  const int blk = blockIdx.x;
  const int bg = blk >> 7;
  const int s = blk & 127;
  const int lane = tid & 63;
  const int wave = tid >> 6;

  // load Wh slice once: block col c -> global col (c>>3)*1024 + s*8 + (c&7)
#pragma unroll
  for (int r = 0; r < 16; ++r) {
    int cid = tid + (r << 8);
    int c = cid >> 7, kc = cid & 127;
    int gcol = ((c >> 3) << 10) + s * 8 + (c & 7);
    uint4v v = *(const uint4v*)(whT + (size_t)gcol * 1024 + kc * 8);
    *(uint4v*)&wh_s[c][kc * 8] = v;
  }

  const int b_l = tid >> 3;  // 0..31
  const int u = tid & 7;     // 0..7
  const int bG = bg * 32 + b_l;
  const int n = s * 8 + u;
  float c_val = c0[(size_t)bG * 1024 + n];
  const float pf = wcf[n], pi = wci[n], po = wco[n];

  const int l15 = lane & 15;
  const int kg = (lane >> 4) * 8;
  const int l31 = lane & 31;
  const int lhi = lane >> 5;
  const int bg32 = bg * 32;

  // prefetch xp for t=0
  const size_t xbase0 = (size_t)bG * 4096 + n;
  ushort px0 = xp[xbase0], px1 = xp[xbase0 + 1024];
  ushort px2 = xp[xbase0 + 2048], px3 = xp[xbase0 + 3072];

  __syncthreads();

  for (int t = 0; t < 512; ++t) {
    // ---- poll+stage own K-window (4 chunks) from tagged slots ----
    {
      const unsigned target = (unsigned)t;
      const u64* tbuf = tb + ((size_t)(t & 1) << 15);
      unsigned done = 0;  // per-lane, 8 groups x 8 slots
      for (;;) {
#pragma unroll
        for (int g = 0; g < 8; ++g) {
          if (done & (1u << g)) continue;
          const int cg = (wave << 2) + (g >> 1);       // global chunk
          const size_t jcol = ((size_t)cg << 5) + l31;  // slot col (same all k)
          u64 v[8];
#pragma unroll
          for (int k = 0; k < 8; ++k) {
            int b = (lhi + (g << 4) + (k << 1)) & 31;
            v[k] = __hip_atomic_load(tbuf + (((size_t)(bg32 + b)) << 9) + jcol,
                                     __ATOMIC_RELAXED, __HIP_MEMORY_SCOPE_AGENT);
          }
          bool ok = true;
#pragma unroll
          for (int k = 0; k < 8; ++k) ok &= ((unsigned)(v[k] >> 32) == target);
          if (ok) {
#pragma unroll
            for (int k = 0; k < 8; ++k) {
              int b = (lhi + (g << 4) + (k << 1)) & 31;
              *(unsigned*)&h_s[b][(cg << 6) + (l31 << 1)] = (unsigned)v[k];
            }
            done |= 1u << g;
          }
        }
        if (__ballot(done != 0xFFu) == 0ull) break;
      }
    }
    asm volatile("s_waitcnt lgkmcnt(0)" ::: "memory");  // staged writes complete

    // ---- MFMA own K-window (4 chunks x 2 k-steps x 4 tiles) ----
    f32x4 a00 = {}, a01 = {}, a10 = {}, a11 = {};
#pragma unroll
    for (int c = 0; c < 4; ++c) {
#pragma unroll
      for (int kk = 0; kk < 2; ++kk) {
        const int ko = (((wave << 2) + c) << 6) + (kk << 5) + kg;
        short8 fa0 = *(const short8*)&h_s[l15][ko];
        short8 fa1 = *(const short8*)&h_s[16 + l15][ko];
        short8 fb0 = *(const short8*)&wh_s[l15][ko];
        short8 fb1 = *(const short8*)&wh_s[16 + l15][ko];
        a00 = __builtin_amdgcn_mfma_f32_16x16x32_bf16(fa0, fb0, a00, 0, 0, 0);
        a01 = __builtin_amdgcn_mfma_f32_16x16x32_bf16(fa0, fb1, a01, 0, 0, 0);
        a10 = __builtin_amdgcn_mfma_f32_16x16x32_bf16(fa1, fb0, a10, 0, 0, 0);
        a11 = __builtin_amdgcn_mfma_f32_16x16x32_bf16(fa1, fb1, a11, 0, 0, 0);
      }
    }

    // ---- write per-wave partial gates ----
#pragma unroll
    for (int r = 0; r < 4; ++r) {
      const int rr = ((lane >> 4) << 2) + r;
      G[wave][rr][l15]           = a00[r];
      G[wave][rr][16 + l15]      = a01[r];
      G[wave][16 + rr][l15]      = a10[r];
      G[wave][16 + rr][16 + l15] = a11[r];
    }
    LGKM_BAR();  // sync#1: G partials ready (LDS-only, no vmem drain)

    // ---- elementwise gate update: one (batch, unit) per thread ----
    float gf = (G[0][b_l][u]      + G[1][b_l][u])      + (G[2][b_l][u]      + G[3][b_l][u])      + bf2f(px0);
    float gi = (G[0][b_l][8 + u]  + G[1][b_l][8 + u])  + (G[2][b_l][8 + u]  + G[3][b_l][8 + u])  + bf2f(px1);
    float go = (G[0][b_l][16 + u] + G[1][b_l][16 + u]) + (G[2][b_l][16 + u] + G[3][b_l][16 + u]) + bf2f(px2);
    float gc = (G[0][b_l][24 + u] + G[1][b_l][24 + u]) + (G[2][b_l][24 + u] + G[3][b_l][24 + u]) + bf2f(px3);
    float f = 1.f / (1.f + __expf(-(gf + pf * c_val)));
    float i = 1.f / (1.f + __expf(-(gi + pi * c_val)));
    float ct = 2.f / (1.f + __expf(-2.f * gc)) - 1.f;
    float cn = f * c_val + i * ct;
    float o = 1.f / (1.f + __expf(-(go + po * cn)));
    float h = o * (2.f / (1.f + __expf(-2.f * cn)) - 1.f);
    c_val = cn;

    // ---- publish h ASAP: ONE tagged sc1 store per even thread, fire-and-forget ----
    if (t < 511) {
      float hx = __shfl_xor(h, 1);
      if ((u & 1) == 0) {
        u64 val = (u64)((unsigned)f2bf(h) | ((unsigned)f2bf(hx) << 16)) |
                  ((u64)(unsigned)(t + 1) << 32);
        u64* dst = tb + ((size_t)((t + 1) & 1) << 15) + ((size_t)bG << 9) +
                   (s << 2) + (u >> 1);
        __hip_atomic_store(dst, val, __ATOMIC_RELAXED, __HIP_MEMORY_SCOPE_AGENT);
      }
    }
    LGKM_BAR();  // sync#2: G(t) reads done before next iter's G writes

    // off critical path: out store + next xp prefetch
    out[(size_t)(bG * 512 + t) * 1024 + n] = h;
    if (t < 511) {
      size_t xb = xbase0 + (size_t)(t + 1) * 262144;  // 64*4096
      px0 = xp[xb]; px1 = xp[xb + 1024]; px2 = xp[xb + 2048]; px3 = xp[xb + 3072];
    }
  }
}

// ---------------- launcher ----------------
extern "C" void kernel_launch(void* const* d_in, const int* in_sizes, int n_in,
                              void* d_out, int out_size, void* d_ws, size_t ws_size,
                              hipStream_t stream) {
  const float* x = (const float*)d_in[0];
  const float* c0 = (const float*)d_in[1];
  const float* h0 = (const float*)d_in[2];
  const float* Wfx = (const float*)d_in[3];
  const float* bfp = (const float*)d_in[4];
  const float* Wix = (const float*)d_in[5];
  const float* bip = (const float*)d_in[6];
  const float* Wox = (const float*)d_in[7];
  const float* bop = (const float*)d_in[8];
  const float* Wcx = (const float*)d_in[9];
  const float* bcp = (const float*)d_in[10];
  const float* Wfh = (const float*)d_in[11];
  const float* Wih = (const float*)d_in[12];
  const float* Woh = (const float*)d_in[13];
  const float* Wch = (const float*)d_in[14];
  const float* wcf = (const float*)d_in[15];
  const float* wci = (const float*)d_in[16];
  const float* wco = (const float*)d_in[17];
  float* out = (float*)d_out;

  char* ws = (char*)d_ws;
  ushort* xp = (ushort*)(ws + 0);              // 268,435,456 B
  ushort* WxT = (ushort*)(ws + 268435456ULL);  // 4,194,304 B (dead after gemm_xp)
  u64* tb = (u64*)(ws + 268435456ULL);         // 524,288 B, REUSES WxT region
  ushort* WhT = (ushort*)(ws + 272629760ULL);  // 8,388,608 B
  float* bias = (float*)(ws + 281018368ULL);   // 16,384 B
  if (ws_size < 281034752ULL) return;

  const float* wxs[4] = {Wfx, Wix, Wox, Wcx};
  for (int g = 0; g < 4; ++g)
    transpose_cvt<<<dim3(32, 16), dim3(32, 8), 0, stream>>>(
        wxs[g], WxT + (size_t)g * 1024 * 512, 512, 1024);
  const float* whs[4] = {Wfh, Wih, Woh, Wch};
  for (int g = 0; g < 4; ++g)
    transpose_cvt<<<dim3(32, 32), dim3(32, 8), 0, stream>>>(
        whs[g], WhT + (size_t)g * 1024 * 1024, 1024, 1024);
  concat_bias<<<16, 256, 0, stream>>>(bfp, bip, bop, bcp, bias);
  gemm_xp<<<dim3(32, 256), 256, 0, stream>>>(x, WxT, bias, xp);

  // WxT is dead now; its region becomes the tagged h buffer.
  hipMemsetAsync(tb, 0xFF, 524288, stream);              // tags -> 0xFFFFFFFF
  init_tagged<<<128, 256, 0, stream>>>(h0, (u64*)tb);    // parity 0 <- h0, tag 0

  void* args[8];
  args[0] = (void*)&xp;
  args[1] = (void*)&WhT;
  args[2] = (void*)&c0;
  args[3] = (void*)&wcf;
  args[4] = (void*)&wci;
  args[5] = (void*)&wco;
  args[6] = (void*)&tb;
  args[7] = (void*)&out;
  hipLaunchCooperativeKernel((void*)lstm_rec, dim3(256), dim3(256), args, 0, stream);
}